// Round 11
// baseline (327.715 us; speedup 1.0000x reference)
//
#include <hip/hip_runtime.h>
#include <hip/hip_fp16.h>
#include <math.h>

#define D_IN 16
#define D    64
#define H    128
#define EPSL 1e-5f

typedef _Float16 h2v __attribute__((ext_vector_type(2)));

// dot2: d = a.x*b.x + a.y*b.y + c, fp16 inputs, fp32 accumulate
__device__ __forceinline__ float dot2f(unsigned int a, unsigned int b, float c)
{
#if __has_builtin(__builtin_amdgcn_fdot2)
    return __builtin_amdgcn_fdot2(__builtin_bit_cast(h2v, a),
                                  __builtin_bit_cast(h2v, b), c, false);
#else
    __half2 ha = *reinterpret_cast<__half2*>(&a);
    __half2 hb = *reinterpret_cast<__half2*>(&b);
    float2 fa = __half22float2(ha), fb = __half22float2(hb);
    return fmaf(fa.x, fb.x, fmaf(fa.y, fb.y, c));
#endif
}

__device__ __forceinline__ unsigned int packh2(float x, float y)
{
    __half2 p = __floats2half2_rn(x, y);
    return *reinterpret_cast<unsigned int*>(&p);
}

// =======================================================================
// Preprocessing (round-6 proven): hist + hierarchical scan + XCD-grouped
// fill. k_zero2 merges the two zero launches (cnt + fill).
// =======================================================================

__global__ void k_zero2(int* __restrict__ a, int* __restrict__ b, int n)
{
    int i = blockIdx.x * blockDim.x + threadIdx.x;
    if (i < n) { a[i] = 0; b[i] = 0; }
}

__global__ void k_hist(const int* __restrict__ dst, int* __restrict__ cnt, int E)
{
    int i = blockIdx.x * blockDim.x + threadIdx.x;
    if (i < E) atomicAdd(&cnt[dst[i]], 1);
}

__global__ void k_scan_blk(const int* __restrict__ cnt, int* __restrict__ off,
                           int* __restrict__ bsum, int N)
{
    __shared__ int sm[256];
    int t = threadIdx.x;
    int g = blockIdx.x * 256 + t;
    int v = (g < N) ? cnt[g] : 0;
    sm[t] = v;
    __syncthreads();
    for (int d2 = 1; d2 < 256; d2 <<= 1) {
        int u = (t >= d2) ? sm[t - d2] : 0;
        __syncthreads();
        sm[t] += u;
        __syncthreads();
    }
    if (g < N) off[g + 1] = sm[t];
    if (t == 255) bsum[blockIdx.x] = sm[255];
}

__global__ void k_scan_top(int* __restrict__ bsum, int G)
{
    __shared__ int sm[1024];
    int t = threadIdx.x;
    int v = (t < G) ? bsum[t] : 0;
    sm[t] = v;
    __syncthreads();
    for (int d2 = 1; d2 < 1024; d2 <<= 1) {
        int u = (t >= d2) ? sm[t - d2] : 0;
        __syncthreads();
        sm[t] += u;
        __syncthreads();
    }
    if (t < G) bsum[t] = sm[t] - v;   // exclusive
}

__global__ void k_scan_add(int* __restrict__ off, const int* __restrict__ bsum, int N)
{
    int g = blockIdx.x * 256 + threadIdx.x;
    if (g < N) off[g + 1] += bsum[blockIdx.x];
    if (g == 0) off[0] = 0;
}

__global__ __launch_bounds__(256) void k_fill_x(const int* __restrict__ src,
                                                const int* __restrict__ dst,
                                                const int* __restrict__ off,
                                                int* __restrict__ fill,
                                                int* __restrict__ csr, int E)
{
    int g = blockIdx.x & 7;
    int j = blockIdx.x >> 3;
    int J = gridDim.x >> 3;
    for (int e = j * 256 + threadIdx.x; e < E; e += J * 256) {
        int d = dst[e];
        if (((d >> 4) & 7) == g) {
            int p = atomicAdd(&fill[d], 1);
            csr[off[d] + p] = src[e];
        }
    }
}

// =======================================================================
// Weight prep: pack wa/wb into k-paired fp16 (round-10 proven).
// =======================================================================
__global__ void k_prep_w(const float* __restrict__ wa, const float* __restrict__ wb,
                         unsigned int* __restrict__ wap, unsigned int* __restrict__ wbp,
                         int L)
{
    int idx = blockIdx.x * blockDim.x + threadIdx.x;
    if (idx >= L * 8192) return;
    int l = idx >> 13;
    int r = idx & 8191;
    if (r < 4096) {
        int k2 = r >> 7, c = r & 127;
        const float* base = wa + (size_t)l * D * H;
        wap[(size_t)l * 4096 + r] = packh2(base[(2 * k2) * H + c],
                                           base[(2 * k2 + 1) * H + c]);
    } else {
        r -= 4096;
        int k2 = r >> 6, j = r & 63;
        const float* base = wb + (size_t)l * H * D;
        wbp[(size_t)l * 4096 + r] = packh2(base[(2 * k2) * D + j],
                                           base[(2 * k2 + 1) * D + j]);
    }
}

// =======================================================================
// GEMM-tiled MLP v4 (round-10 proven, unchanged): fp16-pair operands,
// v_dot2_f32_f16, 24KB LDS, quad-XOR swizzle, fp16 m output.
// =======================================================================
__global__ __launch_bounds__(256) void k_mlp(const float* __restrict__ h,
                                             const unsigned int* __restrict__ wap, // [32][128] pairs
                                             const float* __restrict__ ba,         // [128]
                                             const unsigned int* __restrict__ wbp, // [64][64] pairs
                                             const float* __restrict__ bb,         // [64]
                                             __half* __restrict__ m, int N)
{
    __shared__ __align__(16) unsigned int hT2[32 * 64];  // 8KB
    __shared__ __align__(16) unsigned int gT2[64 * 64];  // 16KB

    const int tid  = threadIdx.x;
    const int ch   = tid & 15;
    const int q    = tid >> 4;          // node quad 0..15
    const int base = blockIdx.x * 64;

    // stage h -> hT2 (fp16 pairs, transposed). b32 writes, lanes consecutive.
    {
        int sn = tid & 63;
        int sc = tid >> 6;              // k-chunk 16 floats -> 8 pair rows
        int gn = min(base + sn, N - 1);
        const float4* hp = (const float4*)(h + (size_t)gn * D + sc * 16);
        float4 A = hp[0], B = hp[1], C = hp[2], Dv = hp[3];
        unsigned int* w = hT2 + (sc * 8) * 64 + sn;
        w[0 * 64] = packh2(A.x, A.y);  w[1 * 64] = packh2(A.z, A.w);
        w[2 * 64] = packh2(B.x, B.y);  w[3 * 64] = packh2(B.z, B.w);
        w[4 * 64] = packh2(C.x, C.y);  w[5 * 64] = packh2(C.z, C.w);
        w[6 * 64] = packh2(Dv.x, Dv.y); w[7 * 64] = packh2(Dv.z, Dv.w);
    }
    __syncthreads();

    // phase 1: acc[node i][hid c] for hidden channels 8ch..8ch+7, k2=0..31
    float acc[4][8];
#pragma unroll
    for (int i = 0; i < 4; ++i)
#pragma unroll
        for (int c = 0; c < 8; ++c) acc[i][c] = 0.f;

#pragma unroll 4
    for (int k2 = 0; k2 < 32; ++k2) {
        const unsigned int* wr = wap + k2 * 128 + ch * 8;
        uint4 w0 = *(const uint4*)(wr);
        uint4 w1 = *(const uint4*)(wr + 4);
        uint4 hh = *(const uint4*)(hT2 + k2 * 64 + q * 4);   // 4 nodes' pairs
#define P1(i, hv) \
        acc[i][0]=dot2f(hv,w0.x,acc[i][0]); acc[i][1]=dot2f(hv,w0.y,acc[i][1]); \
        acc[i][2]=dot2f(hv,w0.z,acc[i][2]); acc[i][3]=dot2f(hv,w0.w,acc[i][3]); \
        acc[i][4]=dot2f(hv,w1.x,acc[i][4]); acc[i][5]=dot2f(hv,w1.y,acc[i][5]); \
        acc[i][6]=dot2f(hv,w1.z,acc[i][6]); acc[i][7]=dot2f(hv,w1.w,acc[i][7]);
        P1(0, hh.x) P1(1, hh.y) P1(2, hh.z) P1(3, hh.w)
#undef P1
    }

    // bias + relu + pack to gT2 pair-rows r2 = 4ch+cc, chunk-swizzled b128
    {
        float4 b0v = *(const float4*)(ba + ch * 8);
        float4 b1v = *(const float4*)(ba + ch * 8 + 4);
        float bav[8] = {b0v.x, b0v.y, b0v.z, b0v.w, b1v.x, b1v.y, b1v.z, b1v.w};
#pragma unroll
        for (int cc = 0; cc < 4; ++cc) {
            int c0 = 2 * cc, c1 = 2 * cc + 1;
            int r2 = ch * 4 + cc;
            int chunk = q ^ (r2 & 15);
            uint4 t;
            t.x = packh2(fmaxf(acc[0][c0] + bav[c0], 0.f), fmaxf(acc[0][c1] + bav[c1], 0.f));
            t.y = packh2(fmaxf(acc[1][c0] + bav[c0], 0.f), fmaxf(acc[1][c1] + bav[c1], 0.f));
            t.z = packh2(fmaxf(acc[2][c0] + bav[c0], 0.f), fmaxf(acc[2][c1] + bav[c1], 0.f));
            t.w = packh2(fmaxf(acc[3][c0] + bav[c0], 0.f), fmaxf(acc[3][c1] + bav[c1], 0.f));
            *(uint4*)(gT2 + r2 * 64 + chunk * 4) = t;
        }
    }
    __syncthreads();

    // phase 2: o[node i][out j] for out channels 4ch..4ch+3, k2=0..63
    float oo[4][4];
#pragma unroll
    for (int i = 0; i < 4; ++i)
#pragma unroll
        for (int j = 0; j < 4; ++j) oo[i][j] = 0.f;

#pragma unroll 8
    for (int k2 = 0; k2 < 64; ++k2) {
        uint4 w = *(const uint4*)(wbp + k2 * 64 + ch * 4);
        int chunk = q ^ (k2 & 15);
        uint4 g = *(const uint4*)(gT2 + k2 * 64 + chunk * 4);
#define P2(i, gv) \
        oo[i][0]=dot2f(gv,w.x,oo[i][0]); oo[i][1]=dot2f(gv,w.y,oo[i][1]); \
        oo[i][2]=dot2f(gv,w.z,oo[i][2]); oo[i][3]=dot2f(gv,w.w,oo[i][3]);
        P2(0, g.x) P2(1, g.y) P2(2, g.z) P2(3, g.w)
#undef P2
    }

    // bias + SiLU + LN (reduce across the 16 in-wave channel owners)
    float4 bbv = *(const float4*)(bb + ch * 4);
    float bz[4] = {bbv.x, bbv.y, bbv.z, bbv.w};
    float s[4], qv[4];
#pragma unroll
    for (int i = 0; i < 4; ++i) {
        float ss = 0.f, qq = 0.f;
#pragma unroll
        for (int j = 0; j < 4; ++j) {
            float t = oo[i][j] + bz[j];
            t = t / (1.f + __expf(-t));
            oo[i][j] = t;
            ss += t;
            qq = fmaf(t, t, qq);
        }
        s[i] = ss; qv[i] = qq;
    }

#pragma unroll
    for (int d2 = 1; d2 < 16; d2 <<= 1) {
#pragma unroll
        for (int i = 0; i < 4; ++i) {
            s[i]  += __shfl_xor(s[i],  d2, 64);
            qv[i] += __shfl_xor(qv[i], d2, 64);
        }
    }

#pragma unroll
    for (int i = 0; i < 4; ++i) {
        float mu  = s[i] * (1.f / D);
        float var = qv[i] * (1.f / D) - mu * mu;
        float inv = rsqrtf(var + EPSL);
        int node = base + q * 4 + i;
        if (node < N) {
            uint2 pk;
            pk.x = packh2((oo[i][0] - mu) * inv, (oo[i][1] - mu) * inv);
            pk.y = packh2((oo[i][2] - mu) * inv, (oo[i][3] - mu) * inv);
            *(uint2*)(m + (size_t)node * D + ch * 4) = pk;   // 8B store
        }
    }
}

// =======================================================================
// Initial embedding (round-7 proven, unchanged; fp32 h output).
// =======================================================================
__global__ __launch_bounds__(256) void k_init(const float* __restrict__ x,
                                              const float* __restrict__ w0,  // [16][64]
                                              const float* __restrict__ b0,
                                              const float* __restrict__ w1,  // [64][64]
                                              const float* __restrict__ b1,
                                              float* __restrict__ h, int N)
{
    __shared__ __align__(16) float xT[D_IN * 64];
    __shared__ __align__(16) float gT[D * 64];

    const int tid  = threadIdx.x;
    const int ch   = tid & 15;
    const int q    = tid >> 4;
    const int base = blockIdx.x * 64;

    {
        int sn = tid & 63;
        int sc = tid >> 6;
        int gn = min(base + sn, N - 1);
        float4 xv = *(const float4*)(x + (size_t)gn * D_IN + sc * 4);
        float* w = xT + (sc * 4) * 64 + sn;
        w[0*64] = xv.x; w[1*64] = xv.y; w[2*64] = xv.z; w[3*64] = xv.w;
    }
    __syncthreads();

    float acc[4][4];
#pragma unroll
    for (int i = 0; i < 4; ++i)
#pragma unroll
        for (int c = 0; c < 4; ++c) acc[i][c] = 0.f;

#pragma unroll
    for (int k = 0; k < D_IN; ++k) {
        float4 w = *(const float4*)(w0 + k * D + ch * 4);
        float4 xv = *(const float4*)(xT + k * 64 + q * 4);
#define PP(i, xc) \
        acc[i][0]=fmaf(xc,w.x,acc[i][0]); acc[i][1]=fmaf(xc,w.y,acc[i][1]); \
        acc[i][2]=fmaf(xc,w.z,acc[i][2]); acc[i][3]=fmaf(xc,w.w,acc[i][3]);
        PP(0, xv.x) PP(1, xv.y) PP(2, xv.z) PP(3, xv.w)
#undef PP
    }

    {
        float4 b0v = *(const float4*)(b0 + ch * 4);
        float bav[4] = {b0v.x, b0v.y, b0v.z, b0v.w};
        int chunk = q ^ (ch >> 1);      // r = 4ch+c -> r>>3 = ch>>1
#pragma unroll
        for (int c = 0; c < 4; ++c) {
            int r = ch * 4 + c;
            float4 t;
            t.x = fmaxf(acc[0][c] + bav[c], 0.f);
            t.y = fmaxf(acc[1][c] + bav[c], 0.f);
            t.z = fmaxf(acc[2][c] + bav[c], 0.f);
            t.w = fmaxf(acc[3][c] + bav[c], 0.f);
            *(float4*)(gT + r * 64 + chunk * 4) = t;
        }
    }
    __syncthreads();

    float4 o0 = {0,0,0,0}, o1 = {0,0,0,0}, o2 = {0,0,0,0}, o3 = {0,0,0,0};
#pragma unroll 8
    for (int k = 0; k < D; ++k) {
        float4 w = *(const float4*)(w1 + k * D + ch * 4);
        int chunk = q ^ ((k >> 3) & 15);
        float4 g = *(const float4*)(gT + k * 64 + chunk * 4);
        o0.x=fmaf(g.x,w.x,o0.x); o0.y=fmaf(g.x,w.y,o0.y); o0.z=fmaf(g.x,w.z,o0.z); o0.w=fmaf(g.x,w.w,o0.w);
        o1.x=fmaf(g.y,w.x,o1.x); o1.y=fmaf(g.y,w.y,o1.y); o1.z=fmaf(g.y,w.z,o1.z); o1.w=fmaf(g.y,w.w,o1.w);
        o2.x=fmaf(g.z,w.x,o2.x); o2.y=fmaf(g.z,w.y,o2.y); o2.z=fmaf(g.z,w.z,o2.z); o2.w=fmaf(g.z,w.w,o2.w);
        o3.x=fmaf(g.w,w.x,o3.x); o3.y=fmaf(g.w,w.y,o3.y); o3.z=fmaf(g.w,w.z,o3.z); o3.w=fmaf(g.w,w.w,o3.w);
    }

    float4 bbv = *(const float4*)(b1 + ch * 4);
    float s[4], qv[4];
#define FIN(i, ov) { \
        ov.x += bbv.x; ov.y += bbv.y; ov.z += bbv.z; ov.w += bbv.w; \
        ov.x = ov.x / (1.f + __expf(-ov.x)); ov.y = ov.y / (1.f + __expf(-ov.y)); \
        ov.z = ov.z / (1.f + __expf(-ov.z)); ov.w = ov.w / (1.f + __expf(-ov.w)); \
        s[i]  = (ov.x + ov.y) + (ov.z + ov.w); \
        qv[i] = fmaf(ov.x, ov.x, fmaf(ov.y, ov.y, fmaf(ov.z, ov.z, ov.w * ov.w))); }
    FIN(0, o0) FIN(1, o1) FIN(2, o2) FIN(3, o3)
#undef FIN

#pragma unroll
    for (int d2 = 1; d2 < 16; d2 <<= 1) {
#pragma unroll
        for (int i = 0; i < 4; ++i) {
            s[i]  += __shfl_xor(s[i],  d2, 64);
            qv[i] += __shfl_xor(qv[i], d2, 64);
        }
    }

#pragma unroll
    for (int i = 0; i < 4; ++i) {
        float mu  = s[i] * (1.f / D);
        float var = qv[i] * (1.f / D) - mu * mu;
        float inv = rsqrtf(var + EPSL);
        int node = base + q * 4 + i;
        if (node < N) {
            float4 ov = (i == 0) ? o0 : (i == 1) ? o1 : (i == 2) ? o2 : o3;
            float4 outv;
            outv.x = (ov.x - mu) * inv;
            outv.y = (ov.y - mu) * inv;
            outv.z = (ov.z - mu) * inv;
            outv.w = (ov.w - mu) * inv;
            *(float4*)(h + (size_t)node * D + ch * 4) = outv;
        }
    }
}

// =======================================================================
// Aggregation v2: ONE WAVE PER NODE. Lane (es,c): es=(tid>>4)&3 edge slot,
// c=tid&15 channel pair group. Edge loop length ~deg/4 (was deg), unroll 2
// -> 8 gather lines in flight per lane-quad; grid 4x (12500 blocks) -> 4x
// machine-wide outstanding misses on the L2/L3-resident gather. Reduce
// across edge slots via shfl_xor(16/32); es==0 lanes do the h RMW.
// =======================================================================
__global__ __launch_bounds__(256) void k_agg(const __half* __restrict__ m,
                                             const int* __restrict__ csr,
                                             const int* __restrict__ off,
                                             float* __restrict__ h, int N)
{
    int wv = threadIdx.x >> 6;          // node slot within block
    int es = (threadIdx.x >> 4) & 3;    // edge slot
    int c  = threadIdx.x & 15;          // channel pair group
    int node = blockIdx.x * 4 + wv;
    if (node >= N) return;

    int b  = off[node];
    int e2 = off[node + 1];
    float4 s0 = {0.f, 0.f, 0.f, 0.f};
    float4 s1 = {0.f, 0.f, 0.f, 0.f};
#define GATH(sacc, pv) { \
        float2 u0 = __half22float2(*reinterpret_cast<__half2*>(&pv.x)); \
        float2 u1 = __half22float2(*reinterpret_cast<__half2*>(&pv.y)); \
        sacc.x += u0.x; sacc.y += u0.y; sacc.z += u1.x; sacc.w += u1.y; }
    int e = b + es;
    for (; e + 4 < e2; e += 8) {
        int sn0 = csr[e];
        int sn1 = csr[e + 4];
        int2 p0 = ((const int2*)(m + (size_t)sn0 * D))[c];
        int2 p1 = ((const int2*)(m + (size_t)sn1 * D))[c];
        GATH(s0, p0) GATH(s1, p1)
    }
    for (; e < e2; e += 4) {
        int sn = csr[e];
        int2 p = ((const int2*)(m + (size_t)sn * D))[c];
        GATH(s0, p)
    }
#undef GATH
    s0.x += s1.x; s0.y += s1.y; s0.z += s1.z; s0.w += s1.w;

    // reduce across the 4 edge slots (lanes ^16 and ^32)
    s0.x += __shfl_xor(s0.x, 16, 64); s0.x += __shfl_xor(s0.x, 32, 64);
    s0.y += __shfl_xor(s0.y, 16, 64); s0.y += __shfl_xor(s0.y, 32, 64);
    s0.z += __shfl_xor(s0.z, 16, 64); s0.z += __shfl_xor(s0.z, 32, 64);
    s0.w += __shfl_xor(s0.w, 16, 64); s0.w += __shfl_xor(s0.w, 32, 64);

    if (es == 0) {
        float dnm = fmaxf((float)(e2 - b), 1.f);
        float inv = 1.f / dnm;
        float4* hp = (float4*)(h + (size_t)node * D);
        float4 hv = hp[c];
        hv.x = fmaf(s0.x, inv, hv.x);
        hv.y = fmaf(s0.y, inv, hv.y);
        hv.z = fmaf(s0.z, inv, hv.z);
        hv.w = fmaf(s0.w, inv, hv.w);
        hp[c] = hv;
    }
}

extern "C" void kernel_launch(void* const* d_in, const int* in_sizes, int n_in,
                              void* d_out, int out_size, void* d_ws, size_t ws_size,
                              hipStream_t stream)
{
    const float* x  = (const float*)d_in[0];
    const int*   ei = (const int*)d_in[1];
    const float* w0 = (const float*)d_in[2];
    const float* b0 = (const float*)d_in[3];
    const float* w1 = (const float*)d_in[4];
    const float* b1 = (const float*)d_in[5];
    const float* wa = (const float*)d_in[6];
    const float* ba = (const float*)d_in[7];
    const float* wb = (const float*)d_in[8];
    const float* bb = (const float*)d_in[9];

    const int N = in_sizes[0] / D_IN;
    const int E = in_sizes[1] / 2;
    const int L = in_sizes[6] / (D * H);

    const int* src = ei;
    const int* dst = ei + E;

    // workspace layout (256B aligned chunks)
    char* ws = (char*)d_ws;
    size_t o = 0;
    auto carve = [&](size_t bytes) -> char* {
        char* p = ws + o;
        o = (o + bytes + 255) & ~(size_t)255;
        return p;
    };
    __half* m          = (__half*)carve((size_t)N * D * sizeof(__half));
    int*   csr         = (int*)  carve((size_t)E * sizeof(int));
    int*   cnt         = (int*)  carve((size_t)N * sizeof(int));
    int*   fill        = (int*)  carve((size_t)N * sizeof(int));
    int*   offp        = (int*)  carve((size_t)(N + 1) * sizeof(int));
    int*   bsum        = (int*)  carve((size_t)1024 * sizeof(int));
    unsigned int* wap  = (unsigned int*)carve((size_t)L * 4096 * sizeof(unsigned int));
    unsigned int* wbp  = (unsigned int*)carve((size_t)L * 4096 * sizeof(unsigned int));

    float* h = (float*)d_out;

    const int nb = (N + 63) / 64;
    const int G1 = (N + 255) / 256;

    k_zero2<<<(N + 255) / 256, 256, 0, stream>>>(cnt, fill, N);
    k_hist<<<(E + 255) / 256, 256, 0, stream>>>(dst, cnt, E);
    k_scan_blk<<<G1, 256, 0, stream>>>(cnt, offp, bsum, N);
    k_scan_top<<<1, 1024, 0, stream>>>(bsum, G1);
    k_scan_add<<<G1, 256, 0, stream>>>(offp, bsum, N);
    k_fill_x<<<2048, 256, 0, stream>>>(src, dst, offp, fill, csr, E);
    k_prep_w<<<(L * 8192 + 255) / 256, 256, 0, stream>>>(wa, wb, wap, wbp, L);

    k_init<<<nb, 256, 0, stream>>>(x, w0, b0, w1, b1, h, N);

    for (int l = 0; l < L; ++l) {
        k_mlp<<<nb, 256, 0, stream>>>(h, wap + (size_t)l * 4096,
                                      ba + (size_t)l * H,
                                      wbp + (size_t)l * 4096,
                                      bb + (size_t)l * D, m, N);
        k_agg<<<(N + 3) / 4, 256, 0, stream>>>(m, csr, offp, h, N);
    }
}

// Round 12
// 309.474 us; speedup vs baseline: 1.0589x; 1.0589x over previous
//
#include <hip/hip_runtime.h>
#include <hip/hip_fp16.h>
#include <math.h>

#define D_IN 16
#define D    64
#define H    128
#define EPSL 1e-5f

typedef _Float16 h2v __attribute__((ext_vector_type(2)));

// dot2: d = a.x*b.x + a.y*b.y + c, fp16 inputs, fp32 accumulate
__device__ __forceinline__ float dot2f(unsigned int a, unsigned int b, float c)
{
#if __has_builtin(__builtin_amdgcn_fdot2)
    return __builtin_amdgcn_fdot2(__builtin_bit_cast(h2v, a),
                                  __builtin_bit_cast(h2v, b), c, false);
#else
    __half2 ha = *reinterpret_cast<__half2*>(&a);
    __half2 hb = *reinterpret_cast<__half2*>(&b);
    float2 fa = __half22float2(ha), fb = __half22float2(hb);
    return fmaf(fa.x, fb.x, fmaf(fa.y, fb.y, c));
#endif
}

__device__ __forceinline__ unsigned int packh2(float x, float y)
{
    __half2 p = __floats2half2_rn(x, y);
    return *reinterpret_cast<unsigned int*>(&p);
}

// =======================================================================
// Preprocessing: hist + hierarchical scan + XCD-grouped fill.
// Round-12 change: k_fill_x reads the edge stream with NON-TEMPORAL loads.
// Round-11 counters showed WRITE_SIZE 30.8MB for 3.2MB of csr: the 8
// grid-stride passes stream ~25MB of dst through each XCD's 4MB L2,
// evicting partially-filled csr lines mid-fill (~10 evictions/line).
// nt loads keep the stream out of L2 so csr lines coalesce fully.
// =======================================================================

__global__ void k_zero2(int* __restrict__ a, int* __restrict__ b, int n)
{
    int i = blockIdx.x * blockDim.x + threadIdx.x;
    if (i < n) { a[i] = 0; b[i] = 0; }
}

__global__ void k_hist(const int* __restrict__ dst, int* __restrict__ cnt, int E)
{
    int i = blockIdx.x * blockDim.x + threadIdx.x;
    if (i < E) atomicAdd(&cnt[__builtin_nontemporal_load(&dst[i])], 1);
}

__global__ void k_scan_blk(const int* __restrict__ cnt, int* __restrict__ off,
                           int* __restrict__ bsum, int N)
{
    __shared__ int sm[256];
    int t = threadIdx.x;
    int g = blockIdx.x * 256 + t;
    int v = (g < N) ? cnt[g] : 0;
    sm[t] = v;
    __syncthreads();
    for (int d2 = 1; d2 < 256; d2 <<= 1) {
        int u = (t >= d2) ? sm[t - d2] : 0;
        __syncthreads();
        sm[t] += u;
        __syncthreads();
    }
    if (g < N) off[g + 1] = sm[t];
    if (t == 255) bsum[blockIdx.x] = sm[255];
}

__global__ void k_scan_top(int* __restrict__ bsum, int G)
{
    __shared__ int sm[1024];
    int t = threadIdx.x;
    int v = (t < G) ? bsum[t] : 0;
    sm[t] = v;
    __syncthreads();
    for (int d2 = 1; d2 < 1024; d2 <<= 1) {
        int u = (t >= d2) ? sm[t - d2] : 0;
        __syncthreads();
        sm[t] += u;
        __syncthreads();
    }
    if (t < G) bsum[t] = sm[t] - v;   // exclusive
}

__global__ void k_scan_add(int* __restrict__ off, const int* __restrict__ bsum, int N)
{
    int g = blockIdx.x * 256 + threadIdx.x;
    if (g < N) off[g + 1] += bsum[blockIdx.x];
    if (g == 0) off[0] = 0;
}

__global__ __launch_bounds__(256) void k_fill_x(const int* __restrict__ src,
                                                const int* __restrict__ dst,
                                                const int* __restrict__ off,
                                                int* __restrict__ fill,
                                                int* __restrict__ csr, int E)
{
    int g = blockIdx.x & 7;
    int j = blockIdx.x >> 3;
    int J = gridDim.x >> 3;
    for (int e = j * 256 + threadIdx.x; e < E; e += J * 256) {
        int d = __builtin_nontemporal_load(&dst[e]);
        if (((d >> 4) & 7) == g) {
            int s = __builtin_nontemporal_load(&src[e]);
            int p = atomicAdd(&fill[d], 1);
            csr[off[d] + p] = s;
        }
    }
}

// =======================================================================
// Weight prep: pack wa/wb into k-paired fp16 (round-10 proven).
// =======================================================================
__global__ void k_prep_w(const float* __restrict__ wa, const float* __restrict__ wb,
                         unsigned int* __restrict__ wap, unsigned int* __restrict__ wbp,
                         int L)
{
    int idx = blockIdx.x * blockDim.x + threadIdx.x;
    if (idx >= L * 8192) return;
    int l = idx >> 13;
    int r = idx & 8191;
    if (r < 4096) {
        int k2 = r >> 7, c = r & 127;
        const float* base = wa + (size_t)l * D * H;
        wap[(size_t)l * 4096 + r] = packh2(base[(2 * k2) * H + c],
                                           base[(2 * k2 + 1) * H + c]);
    } else {
        r -= 4096;
        int k2 = r >> 6, j = r & 63;
        const float* base = wb + (size_t)l * H * D;
        wbp[(size_t)l * 4096 + r] = packh2(base[(2 * k2) * D + j],
                                           base[(2 * k2 + 1) * D + j]);
    }
}

// =======================================================================
// GEMM-tiled MLP v4 (round-10 proven, unchanged): fp16-pair operands,
// v_dot2_f32_f16, 24KB LDS, quad-XOR swizzle, fp16 m output.
// =======================================================================
__global__ __launch_bounds__(256) void k_mlp(const float* __restrict__ h,
                                             const unsigned int* __restrict__ wap, // [32][128] pairs
                                             const float* __restrict__ ba,         // [128]
                                             const unsigned int* __restrict__ wbp, // [64][64] pairs
                                             const float* __restrict__ bb,         // [64]
                                             __half* __restrict__ m, int N)
{
    __shared__ __align__(16) unsigned int hT2[32 * 64];  // 8KB
    __shared__ __align__(16) unsigned int gT2[64 * 64];  // 16KB

    const int tid  = threadIdx.x;
    const int ch   = tid & 15;
    const int q    = tid >> 4;          // node quad 0..15
    const int base = blockIdx.x * 64;

    // stage h -> hT2 (fp16 pairs, transposed). b32 writes, lanes consecutive.
    {
        int sn = tid & 63;
        int sc = tid >> 6;              // k-chunk 16 floats -> 8 pair rows
        int gn = min(base + sn, N - 1);
        const float4* hp = (const float4*)(h + (size_t)gn * D + sc * 16);
        float4 A = hp[0], B = hp[1], C = hp[2], Dv = hp[3];
        unsigned int* w = hT2 + (sc * 8) * 64 + sn;
        w[0 * 64] = packh2(A.x, A.y);  w[1 * 64] = packh2(A.z, A.w);
        w[2 * 64] = packh2(B.x, B.y);  w[3 * 64] = packh2(B.z, B.w);
        w[4 * 64] = packh2(C.x, C.y);  w[5 * 64] = packh2(C.z, C.w);
        w[6 * 64] = packh2(Dv.x, Dv.y); w[7 * 64] = packh2(Dv.z, Dv.w);
    }
    __syncthreads();

    // phase 1: acc[node i][hid c] for hidden channels 8ch..8ch+7, k2=0..31
    float acc[4][8];
#pragma unroll
    for (int i = 0; i < 4; ++i)
#pragma unroll
        for (int c = 0; c < 8; ++c) acc[i][c] = 0.f;

#pragma unroll 4
    for (int k2 = 0; k2 < 32; ++k2) {
        const unsigned int* wr = wap + k2 * 128 + ch * 8;
        uint4 w0 = *(const uint4*)(wr);
        uint4 w1 = *(const uint4*)(wr + 4);
        uint4 hh = *(const uint4*)(hT2 + k2 * 64 + q * 4);   // 4 nodes' pairs
#define P1(i, hv) \
        acc[i][0]=dot2f(hv,w0.x,acc[i][0]); acc[i][1]=dot2f(hv,w0.y,acc[i][1]); \
        acc[i][2]=dot2f(hv,w0.z,acc[i][2]); acc[i][3]=dot2f(hv,w0.w,acc[i][3]); \
        acc[i][4]=dot2f(hv,w1.x,acc[i][4]); acc[i][5]=dot2f(hv,w1.y,acc[i][5]); \
        acc[i][6]=dot2f(hv,w1.z,acc[i][6]); acc[i][7]=dot2f(hv,w1.w,acc[i][7]);
        P1(0, hh.x) P1(1, hh.y) P1(2, hh.z) P1(3, hh.w)
#undef P1
    }

    // bias + relu + pack to gT2 pair-rows r2 = 4ch+cc, chunk-swizzled b128
    {
        float4 b0v = *(const float4*)(ba + ch * 8);
        float4 b1v = *(const float4*)(ba + ch * 8 + 4);
        float bav[8] = {b0v.x, b0v.y, b0v.z, b0v.w, b1v.x, b1v.y, b1v.z, b1v.w};
#pragma unroll
        for (int cc = 0; cc < 4; ++cc) {
            int c0 = 2 * cc, c1 = 2 * cc + 1;
            int r2 = ch * 4 + cc;
            int chunk = q ^ (r2 & 15);
            uint4 t;
            t.x = packh2(fmaxf(acc[0][c0] + bav[c0], 0.f), fmaxf(acc[0][c1] + bav[c1], 0.f));
            t.y = packh2(fmaxf(acc[1][c0] + bav[c0], 0.f), fmaxf(acc[1][c1] + bav[c1], 0.f));
            t.z = packh2(fmaxf(acc[2][c0] + bav[c0], 0.f), fmaxf(acc[2][c1] + bav[c1], 0.f));
            t.w = packh2(fmaxf(acc[3][c0] + bav[c0], 0.f), fmaxf(acc[3][c1] + bav[c1], 0.f));
            *(uint4*)(gT2 + r2 * 64 + chunk * 4) = t;
        }
    }
    __syncthreads();

    // phase 2: o[node i][out j] for out channels 4ch..4ch+3, k2=0..63
    float oo[4][4];
#pragma unroll
    for (int i = 0; i < 4; ++i)
#pragma unroll
        for (int j = 0; j < 4; ++j) oo[i][j] = 0.f;

#pragma unroll 8
    for (int k2 = 0; k2 < 64; ++k2) {
        uint4 w = *(const uint4*)(wbp + k2 * 64 + ch * 4);
        int chunk = q ^ (k2 & 15);
        uint4 g = *(const uint4*)(gT2 + k2 * 64 + chunk * 4);
#define P2(i, gv) \
        oo[i][0]=dot2f(gv,w.x,oo[i][0]); oo[i][1]=dot2f(gv,w.y,oo[i][1]); \
        oo[i][2]=dot2f(gv,w.z,oo[i][2]); oo[i][3]=dot2f(gv,w.w,oo[i][3]);
        P2(0, g.x) P2(1, g.y) P2(2, g.z) P2(3, g.w)
#undef P2
    }

    // bias + SiLU + LN (reduce across the 16 in-wave channel owners)
    float4 bbv = *(const float4*)(bb + ch * 4);
    float bz[4] = {bbv.x, bbv.y, bbv.z, bbv.w};
    float s[4], qv[4];
#pragma unroll
    for (int i = 0; i < 4; ++i) {
        float ss = 0.f, qq = 0.f;
#pragma unroll
        for (int j = 0; j < 4; ++j) {
            float t = oo[i][j] + bz[j];
            t = t / (1.f + __expf(-t));
            oo[i][j] = t;
            ss += t;
            qq = fmaf(t, t, qq);
        }
        s[i] = ss; qv[i] = qq;
    }

#pragma unroll
    for (int d2 = 1; d2 < 16; d2 <<= 1) {
#pragma unroll
        for (int i = 0; i < 4; ++i) {
            s[i]  += __shfl_xor(s[i],  d2, 64);
            qv[i] += __shfl_xor(qv[i], d2, 64);
        }
    }

#pragma unroll
    for (int i = 0; i < 4; ++i) {
        float mu  = s[i] * (1.f / D);
        float var = qv[i] * (1.f / D) - mu * mu;
        float inv = rsqrtf(var + EPSL);
        int node = base + q * 4 + i;
        if (node < N) {
            uint2 pk;
            pk.x = packh2((oo[i][0] - mu) * inv, (oo[i][1] - mu) * inv);
            pk.y = packh2((oo[i][2] - mu) * inv, (oo[i][3] - mu) * inv);
            *(uint2*)(m + (size_t)node * D + ch * 4) = pk;   // 8B store
        }
    }
}

// =======================================================================
// Initial embedding (round-7 proven, unchanged; fp32 h output).
// =======================================================================
__global__ __launch_bounds__(256) void k_init(const float* __restrict__ x,
                                              const float* __restrict__ w0,  // [16][64]
                                              const float* __restrict__ b0,
                                              const float* __restrict__ w1,  // [64][64]
                                              const float* __restrict__ b1,
                                              float* __restrict__ h, int N)
{
    __shared__ __align__(16) float xT[D_IN * 64];
    __shared__ __align__(16) float gT[D * 64];

    const int tid  = threadIdx.x;
    const int ch   = tid & 15;
    const int q    = tid >> 4;
    const int base = blockIdx.x * 64;

    {
        int sn = tid & 63;
        int sc = tid >> 6;
        int gn = min(base + sn, N - 1);
        float4 xv = *(const float4*)(x + (size_t)gn * D_IN + sc * 4);
        float* w = xT + (sc * 4) * 64 + sn;
        w[0*64] = xv.x; w[1*64] = xv.y; w[2*64] = xv.z; w[3*64] = xv.w;
    }
    __syncthreads();

    float acc[4][4];
#pragma unroll
    for (int i = 0; i < 4; ++i)
#pragma unroll
        for (int c = 0; c < 4; ++c) acc[i][c] = 0.f;

#pragma unroll
    for (int k = 0; k < D_IN; ++k) {
        float4 w = *(const float4*)(w0 + k * D + ch * 4);
        float4 xv = *(const float4*)(xT + k * 64 + q * 4);
#define PP(i, xc) \
        acc[i][0]=fmaf(xc,w.x,acc[i][0]); acc[i][1]=fmaf(xc,w.y,acc[i][1]); \
        acc[i][2]=fmaf(xc,w.z,acc[i][2]); acc[i][3]=fmaf(xc,w.w,acc[i][3]);
        PP(0, xv.x) PP(1, xv.y) PP(2, xv.z) PP(3, xv.w)
#undef PP
    }

    {
        float4 b0v = *(const float4*)(b0 + ch * 4);
        float bav[4] = {b0v.x, b0v.y, b0v.z, b0v.w};
        int chunk = q ^ (ch >> 1);      // r = 4ch+c -> r>>3 = ch>>1
#pragma unroll
        for (int c = 0; c < 4; ++c) {
            int r = ch * 4 + c;
            float4 t;
            t.x = fmaxf(acc[0][c] + bav[c], 0.f);
            t.y = fmaxf(acc[1][c] + bav[c], 0.f);
            t.z = fmaxf(acc[2][c] + bav[c], 0.f);
            t.w = fmaxf(acc[3][c] + bav[c], 0.f);
            *(float4*)(gT + r * 64 + chunk * 4) = t;
        }
    }
    __syncthreads();

    float4 o0 = {0,0,0,0}, o1 = {0,0,0,0}, o2 = {0,0,0,0}, o3 = {0,0,0,0};
#pragma unroll 8
    for (int k = 0; k < D; ++k) {
        float4 w = *(const float4*)(w1 + k * D + ch * 4);
        int chunk = q ^ ((k >> 3) & 15);
        float4 g = *(const float4*)(gT + k * 64 + chunk * 4);
        o0.x=fmaf(g.x,w.x,o0.x); o0.y=fmaf(g.x,w.y,o0.y); o0.z=fmaf(g.x,w.z,o0.z); o0.w=fmaf(g.x,w.w,o0.w);
        o1.x=fmaf(g.y,w.x,o1.x); o1.y=fmaf(g.y,w.y,o1.y); o1.z=fmaf(g.y,w.z,o1.z); o1.w=fmaf(g.y,w.w,o1.w);
        o2.x=fmaf(g.z,w.x,o2.x); o2.y=fmaf(g.z,w.y,o2.y); o2.z=fmaf(g.z,w.z,o2.z); o2.w=fmaf(g.z,w.w,o2.w);
        o3.x=fmaf(g.w,w.x,o3.x); o3.y=fmaf(g.w,w.y,o3.y); o3.z=fmaf(g.w,w.z,o3.z); o3.w=fmaf(g.w,w.w,o3.w);
    }

    float4 bbv = *(const float4*)(b1 + ch * 4);
    float s[4], qv[4];
#define FIN(i, ov) { \
        ov.x += bbv.x; ov.y += bbv.y; ov.z += bbv.z; ov.w += bbv.w; \
        ov.x = ov.x / (1.f + __expf(-ov.x)); ov.y = ov.y / (1.f + __expf(-ov.y)); \
        ov.z = ov.z / (1.f + __expf(-ov.z)); ov.w = ov.w / (1.f + __expf(-ov.w)); \
        s[i]  = (ov.x + ov.y) + (ov.z + ov.w); \
        qv[i] = fmaf(ov.x, ov.x, fmaf(ov.y, ov.y, fmaf(ov.z, ov.z, ov.w * ov.w))); }
    FIN(0, o0) FIN(1, o1) FIN(2, o2) FIN(3, o3)
#undef FIN

#pragma unroll
    for (int d2 = 1; d2 < 16; d2 <<= 1) {
#pragma unroll
        for (int i = 0; i < 4; ++i) {
            s[i]  += __shfl_xor(s[i],  d2, 64);
            qv[i] += __shfl_xor(qv[i], d2, 64);
        }
    }

#pragma unroll
    for (int i = 0; i < 4; ++i) {
        float mu  = s[i] * (1.f / D);
        float var = qv[i] * (1.f / D) - mu * mu;
        float inv = rsqrtf(var + EPSL);
        int node = base + q * 4 + i;
        if (node < N) {
            float4 ov = (i == 0) ? o0 : (i == 1) ? o1 : (i == 2) ? o2 : o3;
            float4 outv;
            outv.x = (ov.x - mu) * inv;
            outv.y = (ov.y - mu) * inv;
            outv.z = (ov.z - mu) * inv;
            outv.w = (ov.w - mu) * inv;
            *(float4*)(h + (size_t)node * D + ch * 4) = outv;
        }
    }
}

// ---------------- aggregation: h += segment_mean(m[src], dst) ------------------
// ROUND-10 PROVEN VERSION (round-11's wave-per-node regressed +6us/launch:
// the gather is latency-bound per dependent chain, not MLP-starved; the
// shfl tail + idle-lane RMW + 4x grid cost more than the extra waves won).
// m fp16 (8B per lane per edge); quarter-wave per node, unroll 4.
__global__ __launch_bounds__(256) void k_agg(const __half* __restrict__ m,
                                             const int* __restrict__ csr,
                                             const int* __restrict__ off,
                                             float* __restrict__ h, int N)
{
    int g = threadIdx.x >> 4;
    int c = threadIdx.x & 15;
    int node = blockIdx.x * 16 + g;
    if (node >= N) return;

    int b  = off[node];
    int e2 = off[node + 1];
    float4 s0 = {0.f, 0.f, 0.f, 0.f};
    float4 s1 = {0.f, 0.f, 0.f, 0.f};
    int e = b;
#define GATH(sacc, pv) { \
        float2 u0 = __half22float2(*reinterpret_cast<__half2*>(&pv.x)); \
        float2 u1 = __half22float2(*reinterpret_cast<__half2*>(&pv.y)); \
        sacc.x += u0.x; sacc.y += u0.y; sacc.z += u1.x; sacc.w += u1.y; }
    for (; e + 4 <= e2; e += 4) {
        int sn0 = csr[e], sn1 = csr[e + 1], sn2 = csr[e + 2], sn3 = csr[e + 3];
        int2 p0 = ((const int2*)(m + (size_t)sn0 * D))[c];
        int2 p1 = ((const int2*)(m + (size_t)sn1 * D))[c];
        int2 p2 = ((const int2*)(m + (size_t)sn2 * D))[c];
        int2 p3 = ((const int2*)(m + (size_t)sn3 * D))[c];
        GATH(s0, p0) GATH(s1, p1) GATH(s0, p2) GATH(s1, p3)
    }
    for (; e < e2; ++e) {
        int sn = csr[e];
        int2 p = ((const int2*)(m + (size_t)sn * D))[c];
        GATH(s0, p)
    }
#undef GATH
    s0.x += s1.x; s0.y += s1.y; s0.z += s1.z; s0.w += s1.w;

    float dnm = fmaxf((float)(e2 - b), 1.f);
    float inv = 1.f / dnm;

    float4* hp = (float4*)(h + (size_t)node * D);
    float4 hv = hp[c];
    hv.x = fmaf(s0.x, inv, hv.x);
    hv.y = fmaf(s0.y, inv, hv.y);
    hv.z = fmaf(s0.z, inv, hv.z);
    hv.w = fmaf(s0.w, inv, hv.w);
    hp[c] = hv;
}

extern "C" void kernel_launch(void* const* d_in, const int* in_sizes, int n_in,
                              void* d_out, int out_size, void* d_ws, size_t ws_size,
                              hipStream_t stream)
{
    const float* x  = (const float*)d_in[0];
    const int*   ei = (const int*)d_in[1];
    const float* w0 = (const float*)d_in[2];
    const float* b0 = (const float*)d_in[3];
    const float* w1 = (const float*)d_in[4];
    const float* b1 = (const float*)d_in[5];
    const float* wa = (const float*)d_in[6];
    const float* ba = (const float*)d_in[7];
    const float* wb = (const float*)d_in[8];
    const float* bb = (const float*)d_in[9];

    const int N = in_sizes[0] / D_IN;
    const int E = in_sizes[1] / 2;
    const int L = in_sizes[6] / (D * H);

    const int* src = ei;
    const int* dst = ei + E;

    // workspace layout (256B aligned chunks)
    char* ws = (char*)d_ws;
    size_t o = 0;
    auto carve = [&](size_t bytes) -> char* {
        char* p = ws + o;
        o = (o + bytes + 255) & ~(size_t)255;
        return p;
    };
    __half* m          = (__half*)carve((size_t)N * D * sizeof(__half));
    int*   csr         = (int*)  carve((size_t)E * sizeof(int));
    int*   cnt         = (int*)  carve((size_t)N * sizeof(int));
    int*   fill        = (int*)  carve((size_t)N * sizeof(int));
    int*   offp        = (int*)  carve((size_t)(N + 1) * sizeof(int));
    int*   bsum        = (int*)  carve((size_t)1024 * sizeof(int));
    unsigned int* wap  = (unsigned int*)carve((size_t)L * 4096 * sizeof(unsigned int));
    unsigned int* wbp  = (unsigned int*)carve((size_t)L * 4096 * sizeof(unsigned int));

    float* h = (float*)d_out;

    const int nb = (N + 63) / 64;
    const int G1 = (N + 255) / 256;

    k_zero2<<<(N + 255) / 256, 256, 0, stream>>>(cnt, fill, N);
    k_hist<<<(E + 255) / 256, 256, 0, stream>>>(dst, cnt, E);
    k_scan_blk<<<G1, 256, 0, stream>>>(cnt, offp, bsum, N);
    k_scan_top<<<1, 1024, 0, stream>>>(bsum, G1);
    k_scan_add<<<G1, 256, 0, stream>>>(offp, bsum, N);
    k_fill_x<<<2048, 256, 0, stream>>>(src, dst, offp, fill, csr, E);
    k_prep_w<<<(L * 8192 + 255) / 256, 256, 0, stream>>>(wa, wb, wap, wbp, L);

    k_init<<<nb, 256, 0, stream>>>(x, w0, b0, w1, b1, h, N);

    for (int l = 0; l < L; ++l) {
        k_mlp<<<nb, 256, 0, stream>>>(h, wap + (size_t)l * 4096,
                                      ba + (size_t)l * H,
                                      wbp + (size_t)l * 4096,
                                      bb + (size_t)l * D, m, N);
        k_agg<<<(N + 15) / 16, 256, 0, stream>>>(m, csr, offp, h, N);
    }
}

// Round 13
// 303.377 us; speedup vs baseline: 1.0802x; 1.0201x over previous
//
#include <hip/hip_runtime.h>
#include <hip/hip_fp16.h>
#include <math.h>

#define D_IN 16
#define D    64
#define H    128
#define EPSL 1e-5f

typedef _Float16 h2v __attribute__((ext_vector_type(2)));

// dot2: d = a.x*b.x + a.y*b.y + c, fp16 inputs, fp32 accumulate
__device__ __forceinline__ float dot2f(unsigned int a, unsigned int b, float c)
{
#if __has_builtin(__builtin_amdgcn_fdot2)
    return __builtin_amdgcn_fdot2(__builtin_bit_cast(h2v, a),
                                  __builtin_bit_cast(h2v, b), c, false);
#else
    __half2 ha = *reinterpret_cast<__half2*>(&a);
    __half2 hb = *reinterpret_cast<__half2*>(&b);
    float2 fa = __half22float2(ha), fb = __half22float2(hb);
    return fmaf(fa.x, fb.x, fmaf(fa.y, fb.y, c));
#endif
}

__device__ __forceinline__ unsigned int packh2(float x, float y)
{
    __half2 p = __floats2half2_rn(x, y);
    return *reinterpret_cast<unsigned int*>(&p);
}

// =======================================================================
// Preprocessing: hist + hierarchical scan + XCD-grouped fill.
// Round-13: k_fill_x processes 4 edges/thread/iter (int4 loads). Round-12
// counters (VALU 4.6%, hbm 16%, occ 62%, nt-loads null) showed the kernel
// is dependent-chain latency-bound: one atomicAdd-with-return -> store
// chain in flight per lane. 4 independent edges per iteration -> 4 atomic
// chains in flight, 4x fewer iterations. Traffic unchanged by design.
// =======================================================================

__global__ void k_zero2(int* __restrict__ a, int* __restrict__ b, int n)
{
    int i = blockIdx.x * blockDim.x + threadIdx.x;
    if (i < n) { a[i] = 0; b[i] = 0; }
}

__global__ void k_hist(const int* __restrict__ dst, int* __restrict__ cnt, int E)
{
    int i = blockIdx.x * blockDim.x + threadIdx.x;
    if (i < E) atomicAdd(&cnt[dst[i]], 1);
}

__global__ void k_scan_blk(const int* __restrict__ cnt, int* __restrict__ off,
                           int* __restrict__ bsum, int N)
{
    __shared__ int sm[256];
    int t = threadIdx.x;
    int g = blockIdx.x * 256 + t;
    int v = (g < N) ? cnt[g] : 0;
    sm[t] = v;
    __syncthreads();
    for (int d2 = 1; d2 < 256; d2 <<= 1) {
        int u = (t >= d2) ? sm[t - d2] : 0;
        __syncthreads();
        sm[t] += u;
        __syncthreads();
    }
    if (g < N) off[g + 1] = sm[t];
    if (t == 255) bsum[blockIdx.x] = sm[255];
}

__global__ void k_scan_top(int* __restrict__ bsum, int G)
{
    __shared__ int sm[1024];
    int t = threadIdx.x;
    int v = (t < G) ? bsum[t] : 0;
    sm[t] = v;
    __syncthreads();
    for (int d2 = 1; d2 < 1024; d2 <<= 1) {
        int u = (t >= d2) ? sm[t - d2] : 0;
        __syncthreads();
        sm[t] += u;
        __syncthreads();
    }
    if (t < G) bsum[t] = sm[t] - v;   // exclusive
}

__global__ void k_scan_add(int* __restrict__ off, const int* __restrict__ bsum, int N)
{
    int g = blockIdx.x * 256 + threadIdx.x;
    if (g < N) off[g + 1] += bsum[blockIdx.x];
    if (g == 0) off[0] = 0;
}

// XCD-grouped fill, 4-edge batched. Grid must be a multiple of 8.
__global__ __launch_bounds__(256) void k_fill_x(const int* __restrict__ src,
                                                const int* __restrict__ dst,
                                                const int* __restrict__ off,
                                                int* __restrict__ fill,
                                                int* __restrict__ csr, int E)
{
    int g = blockIdx.x & 7;
    int j = blockIdx.x >> 3;
    int J = gridDim.x >> 3;
    int e0     = (j * 256 + threadIdx.x) * 4;
    int stride = J * 256 * 4;

#define PROC(dv, sv) \
    if (((dv >> 4) & 7) == g) { \
        int o_ = off[dv]; \
        int p_ = atomicAdd(&fill[dv], 1); \
        csr[o_ + p_] = sv; \
    }

    for (int e = e0; e < E; e += stride) {
        if (e + 3 < E) {
            int4 d4 = *(const int4*)(dst + e);
            int4 s4 = *(const int4*)(src + e);
            PROC(d4.x, s4.x)
            PROC(d4.y, s4.y)
            PROC(d4.z, s4.z)
            PROC(d4.w, s4.w)
        } else {
            for (int k = e; k < E; ++k) {
                int dv = dst[k];
                int sv = src[k];
                PROC(dv, sv)
            }
        }
    }
#undef PROC
}

// =======================================================================
// Weight prep: pack wa/wb into k-paired fp16 (round-10 proven).
// =======================================================================
__global__ void k_prep_w(const float* __restrict__ wa, const float* __restrict__ wb,
                         unsigned int* __restrict__ wap, unsigned int* __restrict__ wbp,
                         int L)
{
    int idx = blockIdx.x * blockDim.x + threadIdx.x;
    if (idx >= L * 8192) return;
    int l = idx >> 13;
    int r = idx & 8191;
    if (r < 4096) {
        int k2 = r >> 7, c = r & 127;
        const float* base = wa + (size_t)l * D * H;
        wap[(size_t)l * 4096 + r] = packh2(base[(2 * k2) * H + c],
                                           base[(2 * k2 + 1) * H + c]);
    } else {
        r -= 4096;
        int k2 = r >> 6, j = r & 63;
        const float* base = wb + (size_t)l * H * D;
        wbp[(size_t)l * 4096 + r] = packh2(base[(2 * k2) * D + j],
                                           base[(2 * k2 + 1) * D + j]);
    }
}

// =======================================================================
// GEMM-tiled MLP v4 (round-10 proven, unchanged): fp16-pair operands,
// v_dot2_f32_f16, 24KB LDS, quad-XOR swizzle, fp16 m output.
// =======================================================================
__global__ __launch_bounds__(256) void k_mlp(const float* __restrict__ h,
                                             const unsigned int* __restrict__ wap, // [32][128] pairs
                                             const float* __restrict__ ba,         // [128]
                                             const unsigned int* __restrict__ wbp, // [64][64] pairs
                                             const float* __restrict__ bb,         // [64]
                                             __half* __restrict__ m, int N)
{
    __shared__ __align__(16) unsigned int hT2[32 * 64];  // 8KB
    __shared__ __align__(16) unsigned int gT2[64 * 64];  // 16KB

    const int tid  = threadIdx.x;
    const int ch   = tid & 15;
    const int q    = tid >> 4;          // node quad 0..15
    const int base = blockIdx.x * 64;

    // stage h -> hT2 (fp16 pairs, transposed). b32 writes, lanes consecutive.
    {
        int sn = tid & 63;
        int sc = tid >> 6;              // k-chunk 16 floats -> 8 pair rows
        int gn = min(base + sn, N - 1);
        const float4* hp = (const float4*)(h + (size_t)gn * D + sc * 16);
        float4 A = hp[0], B = hp[1], C = hp[2], Dv = hp[3];
        unsigned int* w = hT2 + (sc * 8) * 64 + sn;
        w[0 * 64] = packh2(A.x, A.y);  w[1 * 64] = packh2(A.z, A.w);
        w[2 * 64] = packh2(B.x, B.y);  w[3 * 64] = packh2(B.z, B.w);
        w[4 * 64] = packh2(C.x, C.y);  w[5 * 64] = packh2(C.z, C.w);
        w[6 * 64] = packh2(Dv.x, Dv.y); w[7 * 64] = packh2(Dv.z, Dv.w);
    }
    __syncthreads();

    // phase 1: acc[node i][hid c] for hidden channels 8ch..8ch+7, k2=0..31
    float acc[4][8];
#pragma unroll
    for (int i = 0; i < 4; ++i)
#pragma unroll
        for (int c = 0; c < 8; ++c) acc[i][c] = 0.f;

#pragma unroll 4
    for (int k2 = 0; k2 < 32; ++k2) {
        const unsigned int* wr = wap + k2 * 128 + ch * 8;
        uint4 w0 = *(const uint4*)(wr);
        uint4 w1 = *(const uint4*)(wr + 4);
        uint4 hh = *(const uint4*)(hT2 + k2 * 64 + q * 4);   // 4 nodes' pairs
#define P1(i, hv) \
        acc[i][0]=dot2f(hv,w0.x,acc[i][0]); acc[i][1]=dot2f(hv,w0.y,acc[i][1]); \
        acc[i][2]=dot2f(hv,w0.z,acc[i][2]); acc[i][3]=dot2f(hv,w0.w,acc[i][3]); \
        acc[i][4]=dot2f(hv,w1.x,acc[i][4]); acc[i][5]=dot2f(hv,w1.y,acc[i][5]); \
        acc[i][6]=dot2f(hv,w1.z,acc[i][6]); acc[i][7]=dot2f(hv,w1.w,acc[i][7]);
        P1(0, hh.x) P1(1, hh.y) P1(2, hh.z) P1(3, hh.w)
#undef P1
    }

    // bias + relu + pack to gT2 pair-rows r2 = 4ch+cc, chunk-swizzled b128
    {
        float4 b0v = *(const float4*)(ba + ch * 8);
        float4 b1v = *(const float4*)(ba + ch * 8 + 4);
        float bav[8] = {b0v.x, b0v.y, b0v.z, b0v.w, b1v.x, b1v.y, b1v.z, b1v.w};
#pragma unroll
        for (int cc = 0; cc < 4; ++cc) {
            int c0 = 2 * cc, c1 = 2 * cc + 1;
            int r2 = ch * 4 + cc;
            int chunk = q ^ (r2 & 15);
            uint4 t;
            t.x = packh2(fmaxf(acc[0][c0] + bav[c0], 0.f), fmaxf(acc[0][c1] + bav[c1], 0.f));
            t.y = packh2(fmaxf(acc[1][c0] + bav[c0], 0.f), fmaxf(acc[1][c1] + bav[c1], 0.f));
            t.z = packh2(fmaxf(acc[2][c0] + bav[c0], 0.f), fmaxf(acc[2][c1] + bav[c1], 0.f));
            t.w = packh2(fmaxf(acc[3][c0] + bav[c0], 0.f), fmaxf(acc[3][c1] + bav[c1], 0.f));
            *(uint4*)(gT2 + r2 * 64 + chunk * 4) = t;
        }
    }
    __syncthreads();

    // phase 2: o[node i][out j] for out channels 4ch..4ch+3, k2=0..63
    float oo[4][4];
#pragma unroll
    for (int i = 0; i < 4; ++i)
#pragma unroll
        for (int j = 0; j < 4; ++j) oo[i][j] = 0.f;

#pragma unroll 8
    for (int k2 = 0; k2 < 64; ++k2) {
        uint4 w = *(const uint4*)(wbp + k2 * 64 + ch * 4);
        int chunk = q ^ (k2 & 15);
        uint4 g = *(const uint4*)(gT2 + k2 * 64 + chunk * 4);
#define P2(i, gv) \
        oo[i][0]=dot2f(gv,w.x,oo[i][0]); oo[i][1]=dot2f(gv,w.y,oo[i][1]); \
        oo[i][2]=dot2f(gv,w.z,oo[i][2]); oo[i][3]=dot2f(gv,w.w,oo[i][3]);
        P2(0, g.x) P2(1, g.y) P2(2, g.z) P2(3, g.w)
#undef P2
    }

    // bias + SiLU + LN (reduce across the 16 in-wave channel owners)
    float4 bbv = *(const float4*)(bb + ch * 4);
    float bz[4] = {bbv.x, bbv.y, bbv.z, bbv.w};
    float s[4], qv[4];
#pragma unroll
    for (int i = 0; i < 4; ++i) {
        float ss = 0.f, qq = 0.f;
#pragma unroll
        for (int j = 0; j < 4; ++j) {
            float t = oo[i][j] + bz[j];
            t = t / (1.f + __expf(-t));
            oo[i][j] = t;
            ss += t;
            qq = fmaf(t, t, qq);
        }
        s[i] = ss; qv[i] = qq;
    }

#pragma unroll
    for (int d2 = 1; d2 < 16; d2 <<= 1) {
#pragma unroll
        for (int i = 0; i < 4; ++i) {
            s[i]  += __shfl_xor(s[i],  d2, 64);
            qv[i] += __shfl_xor(qv[i], d2, 64);
        }
    }

#pragma unroll
    for (int i = 0; i < 4; ++i) {
        float mu  = s[i] * (1.f / D);
        float var = qv[i] * (1.f / D) - mu * mu;
        float inv = rsqrtf(var + EPSL);
        int node = base + q * 4 + i;
        if (node < N) {
            uint2 pk;
            pk.x = packh2((oo[i][0] - mu) * inv, (oo[i][1] - mu) * inv);
            pk.y = packh2((oo[i][2] - mu) * inv, (oo[i][3] - mu) * inv);
            *(uint2*)(m + (size_t)node * D + ch * 4) = pk;   // 8B store
        }
    }
}

// =======================================================================
// Initial embedding (round-7 proven, unchanged; fp32 h output).
// =======================================================================
__global__ __launch_bounds__(256) void k_init(const float* __restrict__ x,
                                              const float* __restrict__ w0,  // [16][64]
                                              const float* __restrict__ b0,
                                              const float* __restrict__ w1,  // [64][64]
                                              const float* __restrict__ b1,
                                              float* __restrict__ h, int N)
{
    __shared__ __align__(16) float xT[D_IN * 64];
    __shared__ __align__(16) float gT[D * 64];

    const int tid  = threadIdx.x;
    const int ch   = tid & 15;
    const int q    = tid >> 4;
    const int base = blockIdx.x * 64;

    {
        int sn = tid & 63;
        int sc = tid >> 6;
        int gn = min(base + sn, N - 1);
        float4 xv = *(const float4*)(x + (size_t)gn * D_IN + sc * 4);
        float* w = xT + (sc * 4) * 64 + sn;
        w[0*64] = xv.x; w[1*64] = xv.y; w[2*64] = xv.z; w[3*64] = xv.w;
    }
    __syncthreads();

    float acc[4][4];
#pragma unroll
    for (int i = 0; i < 4; ++i)
#pragma unroll
        for (int c = 0; c < 4; ++c) acc[i][c] = 0.f;

#pragma unroll
    for (int k = 0; k < D_IN; ++k) {
        float4 w = *(const float4*)(w0 + k * D + ch * 4);
        float4 xv = *(const float4*)(xT + k * 64 + q * 4);
#define PP(i, xc) \
        acc[i][0]=fmaf(xc,w.x,acc[i][0]); acc[i][1]=fmaf(xc,w.y,acc[i][1]); \
        acc[i][2]=fmaf(xc,w.z,acc[i][2]); acc[i][3]=fmaf(xc,w.w,acc[i][3]);
        PP(0, xv.x) PP(1, xv.y) PP(2, xv.z) PP(3, xv.w)
#undef PP
    }

    {
        float4 b0v = *(const float4*)(b0 + ch * 4);
        float bav[4] = {b0v.x, b0v.y, b0v.z, b0v.w};
        int chunk = q ^ (ch >> 1);      // r = 4ch+c -> r>>3 = ch>>1
#pragma unroll
        for (int c = 0; c < 4; ++c) {
            int r = ch * 4 + c;
            float4 t;
            t.x = fmaxf(acc[0][c] + bav[c], 0.f);
            t.y = fmaxf(acc[1][c] + bav[c], 0.f);
            t.z = fmaxf(acc[2][c] + bav[c], 0.f);
            t.w = fmaxf(acc[3][c] + bav[c], 0.f);
            *(float4*)(gT + r * 64 + chunk * 4) = t;
        }
    }
    __syncthreads();

    float4 o0 = {0,0,0,0}, o1 = {0,0,0,0}, o2 = {0,0,0,0}, o3 = {0,0,0,0};
#pragma unroll 8
    for (int k = 0; k < D; ++k) {
        float4 w = *(const float4*)(w1 + k * D + ch * 4);
        int chunk = q ^ ((k >> 3) & 15);
        float4 g = *(const float4*)(gT + k * 64 + chunk * 4);
        o0.x=fmaf(g.x,w.x,o0.x); o0.y=fmaf(g.x,w.y,o0.y); o0.z=fmaf(g.x,w.z,o0.z); o0.w=fmaf(g.x,w.w,o0.w);
        o1.x=fmaf(g.y,w.x,o1.x); o1.y=fmaf(g.y,w.y,o1.y); o1.z=fmaf(g.y,w.z,o1.z); o1.w=fmaf(g.y,w.w,o1.w);
        o2.x=fmaf(g.z,w.x,o2.x); o2.y=fmaf(g.z,w.y,o2.y); o2.z=fmaf(g.z,w.z,o2.z); o2.w=fmaf(g.z,w.w,o2.w);
        o3.x=fmaf(g.w,w.x,o3.x); o3.y=fmaf(g.w,w.y,o3.y); o3.z=fmaf(g.w,w.z,o3.z); o3.w=fmaf(g.w,w.w,o3.w);
    }

    float4 bbv = *(const float4*)(b1 + ch * 4);
    float s[4], qv[4];
#define FIN(i, ov) { \
        ov.x += bbv.x; ov.y += bbv.y; ov.z += bbv.z; ov.w += bbv.w; \
        ov.x = ov.x / (1.f + __expf(-ov.x)); ov.y = ov.y / (1.f + __expf(-ov.y)); \
        ov.z = ov.z / (1.f + __expf(-ov.z)); ov.w = ov.w / (1.f + __expf(-ov.w)); \
        s[i]  = (ov.x + ov.y) + (ov.z + ov.w); \
        qv[i] = fmaf(ov.x, ov.x, fmaf(ov.y, ov.y, fmaf(ov.z, ov.z, ov.w * ov.w))); }
    FIN(0, o0) FIN(1, o1) FIN(2, o2) FIN(3, o3)
#undef FIN

#pragma unroll
    for (int d2 = 1; d2 < 16; d2 <<= 1) {
#pragma unroll
        for (int i = 0; i < 4; ++i) {
            s[i]  += __shfl_xor(s[i],  d2, 64);
            qv[i] += __shfl_xor(qv[i], d2, 64);
        }
    }

#pragma unroll
    for (int i = 0; i < 4; ++i) {
        float mu  = s[i] * (1.f / D);
        float var = qv[i] * (1.f / D) - mu * mu;
        float inv = rsqrtf(var + EPSL);
        int node = base + q * 4 + i;
        if (node < N) {
            float4 ov = (i == 0) ? o0 : (i == 1) ? o1 : (i == 2) ? o2 : o3;
            float4 outv;
            outv.x = (ov.x - mu) * inv;
            outv.y = (ov.y - mu) * inv;
            outv.z = (ov.z - mu) * inv;
            outv.w = (ov.w - mu) * inv;
            *(float4*)(h + (size_t)node * D + ch * 4) = outv;
        }
    }
}

// ---------------- aggregation: h += segment_mean(m[src], dst) ------------------
// Round-10 proven: m fp16 (8B per lane per edge); quarter-wave/node, unroll 4.
__global__ __launch_bounds__(256) void k_agg(const __half* __restrict__ m,
                                             const int* __restrict__ csr,
                                             const int* __restrict__ off,
                                             float* __restrict__ h, int N)
{
    int g = threadIdx.x >> 4;
    int c = threadIdx.x & 15;
    int node = blockIdx.x * 16 + g;
    if (node >= N) return;

    int b  = off[node];
    int e2 = off[node + 1];
    float4 s0 = {0.f, 0.f, 0.f, 0.f};
    float4 s1 = {0.f, 0.f, 0.f, 0.f};
    int e = b;
#define GATH(sacc, pv) { \
        float2 u0 = __half22float2(*reinterpret_cast<__half2*>(&pv.x)); \
        float2 u1 = __half22float2(*reinterpret_cast<__half2*>(&pv.y)); \
        sacc.x += u0.x; sacc.y += u0.y; sacc.z += u1.x; sacc.w += u1.y; }
    for (; e + 4 <= e2; e += 4) {
        int sn0 = csr[e], sn1 = csr[e + 1], sn2 = csr[e + 2], sn3 = csr[e + 3];
        int2 p0 = ((const int2*)(m + (size_t)sn0 * D))[c];
        int2 p1 = ((const int2*)(m + (size_t)sn1 * D))[c];
        int2 p2 = ((const int2*)(m + (size_t)sn2 * D))[c];
        int2 p3 = ((const int2*)(m + (size_t)sn3 * D))[c];
        GATH(s0, p0) GATH(s1, p1) GATH(s0, p2) GATH(s1, p3)
    }
    for (; e < e2; ++e) {
        int sn = csr[e];
        int2 p = ((const int2*)(m + (size_t)sn * D))[c];
        GATH(s0, p)
    }
#undef GATH
    s0.x += s1.x; s0.y += s1.y; s0.z += s1.z; s0.w += s1.w;

    float dnm = fmaxf((float)(e2 - b), 1.f);
    float inv = 1.f / dnm;

    float4* hp = (float4*)(h + (size_t)node * D);
    float4 hv = hp[c];
    hv.x = fmaf(s0.x, inv, hv.x);
    hv.y = fmaf(s0.y, inv, hv.y);
    hv.z = fmaf(s0.z, inv, hv.z);
    hv.w = fmaf(s0.w, inv, hv.w);
    hp[c] = hv;
}

extern "C" void kernel_launch(void* const* d_in, const int* in_sizes, int n_in,
                              void* d_out, int out_size, void* d_ws, size_t ws_size,
                              hipStream_t stream)
{
    const float* x  = (const float*)d_in[0];
    const int*   ei = (const int*)d_in[1];
    const float* w0 = (const float*)d_in[2];
    const float* b0 = (const float*)d_in[3];
    const float* w1 = (const float*)d_in[4];
    const float* b1 = (const float*)d_in[5];
    const float* wa = (const float*)d_in[6];
    const float* ba = (const float*)d_in[7];
    const float* wb = (const float*)d_in[8];
    const float* bb = (const float*)d_in[9];

    const int N = in_sizes[0] / D_IN;
    const int E = in_sizes[1] / 2;
    const int L = in_sizes[6] / (D * H);

    const int* src = ei;
    const int* dst = ei + E;

    // workspace layout (256B aligned chunks)
    char* ws = (char*)d_ws;
    size_t o = 0;
    auto carve = [&](size_t bytes) -> char* {
        char* p = ws + o;
        o = (o + bytes + 255) & ~(size_t)255;
        return p;
    };
    __half* m          = (__half*)carve((size_t)N * D * sizeof(__half));
    int*   csr         = (int*)  carve((size_t)E * sizeof(int));
    int*   cnt         = (int*)  carve((size_t)N * sizeof(int));
    int*   fill        = (int*)  carve((size_t)N * sizeof(int));
    int*   offp        = (int*)  carve((size_t)(N + 1) * sizeof(int));
    int*   bsum        = (int*)  carve((size_t)1024 * sizeof(int));
    unsigned int* wap  = (unsigned int*)carve((size_t)L * 4096 * sizeof(unsigned int));
    unsigned int* wbp  = (unsigned int*)carve((size_t)L * 4096 * sizeof(unsigned int));

    float* h = (float*)d_out;

    const int nb = (N + 63) / 64;
    const int G1 = (N + 255) / 256;

    k_zero2<<<(N + 255) / 256, 256, 0, stream>>>(cnt, fill, N);
    k_hist<<<(E + 255) / 256, 256, 0, stream>>>(dst, cnt, E);
    k_scan_blk<<<G1, 256, 0, stream>>>(cnt, offp, bsum, N);
    k_scan_top<<<1, 1024, 0, stream>>>(bsum, G1);
    k_scan_add<<<G1, 256, 0, stream>>>(offp, bsum, N);
    k_fill_x<<<2048, 256, 0, stream>>>(src, dst, offp, fill, csr, E);
    k_prep_w<<<(L * 8192 + 255) / 256, 256, 0, stream>>>(wa, wb, wap, wbp, L);

    k_init<<<nb, 256, 0, stream>>>(x, w0, b0, w1, b1, h, N);

    for (int l = 0; l < L; ++l) {
        k_mlp<<<nb, 256, 0, stream>>>(h, wap + (size_t)l * 4096,
                                      ba + (size_t)l * H,
                                      wbp + (size_t)l * 4096,
                                      bb + (size_t)l * D, m, N);
        k_agg<<<(N + 15) / 16, 256, 0, stream>>>(m, csr, offp, h, N);
    }
}

// Round 14
// 250.401 us; speedup vs baseline: 1.3088x; 1.2116x over previous
//
#include <hip/hip_runtime.h>
#include <hip/hip_fp16.h>
#include <math.h>

#define D_IN 16
#define D    64
#define H    128
#define EPSL 1e-5f

typedef _Float16 h2v  __attribute__((ext_vector_type(2)));
typedef _Float16 f16x8 __attribute__((ext_vector_type(8)));
typedef float    f32x4v __attribute__((ext_vector_type(4)));

union FU { uint4 u; f16x8 h; };

__device__ __forceinline__ unsigned int packh2(float x, float y)
{
    __half2 p = __floats2half2_rn(x, y);
    return *reinterpret_cast<unsigned int*>(&p);
}

// =======================================================================
// Preprocessing (round-13 proven): hist + hierarchical scan + XCD-grouped
// 4-edge-batched fill. Unchanged.
// =======================================================================

__global__ void k_zero2(int* __restrict__ a, int* __restrict__ b, int n)
{
    int i = blockIdx.x * blockDim.x + threadIdx.x;
    if (i < n) { a[i] = 0; b[i] = 0; }
}

__global__ void k_hist(const int* __restrict__ dst, int* __restrict__ cnt, int E)
{
    int i = blockIdx.x * blockDim.x + threadIdx.x;
    if (i < E) atomicAdd(&cnt[dst[i]], 1);
}

__global__ void k_scan_blk(const int* __restrict__ cnt, int* __restrict__ off,
                           int* __restrict__ bsum, int N)
{
    __shared__ int sm[256];
    int t = threadIdx.x;
    int g = blockIdx.x * 256 + t;
    int v = (g < N) ? cnt[g] : 0;
    sm[t] = v;
    __syncthreads();
    for (int d2 = 1; d2 < 256; d2 <<= 1) {
        int u = (t >= d2) ? sm[t - d2] : 0;
        __syncthreads();
        sm[t] += u;
        __syncthreads();
    }
    if (g < N) off[g + 1] = sm[t];
    if (t == 255) bsum[blockIdx.x] = sm[255];
}

__global__ void k_scan_top(int* __restrict__ bsum, int G)
{
    __shared__ int sm[1024];
    int t = threadIdx.x;
    int v = (t < G) ? bsum[t] : 0;
    sm[t] = v;
    __syncthreads();
    for (int d2 = 1; d2 < 1024; d2 <<= 1) {
        int u = (t >= d2) ? sm[t - d2] : 0;
        __syncthreads();
        sm[t] += u;
        __syncthreads();
    }
    if (t < G) bsum[t] = sm[t] - v;   // exclusive
}

__global__ void k_scan_add(int* __restrict__ off, const int* __restrict__ bsum, int N)
{
    int g = blockIdx.x * 256 + threadIdx.x;
    if (g < N) off[g + 1] += bsum[blockIdx.x];
    if (g == 0) off[0] = 0;
}

// XCD-grouped fill, 4-edge batched (round-13 proven). Grid multiple of 8.
__global__ __launch_bounds__(256) void k_fill_x(const int* __restrict__ src,
                                                const int* __restrict__ dst,
                                                const int* __restrict__ off,
                                                int* __restrict__ fill,
                                                int* __restrict__ csr, int E)
{
    int g = blockIdx.x & 7;
    int j = blockIdx.x >> 3;
    int J = gridDim.x >> 3;
    int e0     = (j * 256 + threadIdx.x) * 4;
    int stride = J * 256 * 4;

#define PROC(dv, sv) \
    if (((dv >> 4) & 7) == g) { \
        int o_ = off[dv]; \
        int p_ = atomicAdd(&fill[dv], 1); \
        csr[o_ + p_] = sv; \
    }

    for (int e = e0; e < E; e += stride) {
        if (e + 3 < E) {
            int4 d4 = *(const int4*)(dst + e);
            int4 s4 = *(const int4*)(src + e);
            PROC(d4.x, s4.x)
            PROC(d4.y, s4.y)
            PROC(d4.z, s4.z)
            PROC(d4.w, s4.w)
        } else {
            for (int k = e; k < E; ++k) {
                int dv = dst[k];
                int sv = src[k];
                PROC(dv, sv)
            }
        }
    }
#undef PROC
}

// =======================================================================
// Weight prep v2: pack wa/wb into MFMA FRAGMENT order (fp16 pairs).
// mfma_f32_16x16x32_f16 operand layout (two concatenated K=16 halves,
// per m156/m162 tr-read mapping): lane l, elems 0-3: k = 4*(l>>4)+e;
// elems 4-7: k = 16 + 4*(l>>4)+(e-4). Fragment stored as 4 uints/lane
// (uint u = fp16 pair (k0, k0+1), k0 = u<2 ? 4g+2u : 16+4g+2(u-2)).
// waf[(ct*2+kb)*64+lane][4]: B-frag for wa col-tile ct (c=16ct+(l&15)),
//   K-block kb (k += 32kb).          8 ct x 2 kb, 16KB/layer.
// wbf[(c2*4+kb)*64+lane][4]: same for wb, 4 col-tiles x 4 K-blocks.
// =======================================================================
__global__ void k_prep_w(const float* __restrict__ wa, const float* __restrict__ wb,
                         unsigned int* __restrict__ waf, unsigned int* __restrict__ wbf,
                         int L)
{
    int idx = blockIdx.x * blockDim.x + threadIdx.x;
    if (idx >= L * 8192) return;
    int l = idx >> 13;
    int r = idx & 8191;
    bool isA = (r < 4096);
    int r2   = isA ? r : r - 4096;
    int u    = r2 & 3;
    int lane = (r2 >> 2) & 63;
    int t    = r2 >> 8;
    int g  = lane >> 4;
    int li = lane & 15;
    int kk = (u < 2) ? (4 * g + 2 * u) : (16 + 4 * g + 2 * (u - 2));
    if (isA) {
        int kb = t & 1, ct = t >> 1;
        int c  = ct * 16 + li;
        int k0 = kb * 32 + kk;
        const float* bse = wa + (size_t)l * D * H;
        waf[(size_t)l * 4096 + r2] = packh2(bse[k0 * H + c], bse[(k0 + 1) * H + c]);
    } else {
        int kb = t & 3, c2 = t >> 2;
        int j  = c2 * 16 + li;
        int k0 = kb * 32 + kk;
        const float* bse = wb + (size_t)l * H * D;
        wbf[(size_t)l * 4096 + r2] = packh2(bse[k0 * D + j], bse[(k0 + 1) * D + j]);
    }
}

// =======================================================================
// MFMA MLP v5: 256 thr, 64-node tile, 4 waves x 16-node stripes.
// Phase 1: C1[64][128] = h[64][64] x wa : per wave 8 col-tiles x 2 MFMA.
// Phase 2: C2[64][64]  = relu(C1) x wb  : per wave 4 col-tiles x 4 MFMA.
// A-frag (h) from LDS fp16 pairs hpk[node][k2] pad-38 (b64-aligned, spread
// banks). Inter-phase P kept f32 in Pf[node][hid] pad-132 (b128-aligned;
// C/D row=4g+reg / col=li maps straight in, phase-2 A-frag reads 2xb128 +
// cvt_pk). C/D mapping col=lane&15,row=4*(lane>>4)+reg is the HW-verified
// one (m89/m91). Epilogue: SiLU + LN (shfl over the 16 li lanes = the 16
// col owners of each node) + fp16 m store.
// Replaces 2048 dot2/thread with 32 MFMA/wave (~160 matrix-pipe cycles).
// =======================================================================
__global__ __launch_bounds__(256) void k_mlp(const float* __restrict__ h,
                                             const unsigned int* __restrict__ waf,
                                             const float* __restrict__ ba,
                                             const unsigned int* __restrict__ wbf,
                                             const float* __restrict__ bb,
                                             __half* __restrict__ m, int N)
{
    __shared__ __align__(16) unsigned int hpk[64 * 38];  // 9.5KB fp16-pair h
    __shared__ __align__(16) float        Pf[64 * 132];  // 33.8KB f32 relu-hid

    const int tid  = threadIdx.x;
    const int w    = tid >> 6;          // wave = 16-node stripe
    const int lane = tid & 63;
    const int g    = lane >> 4;
    const int li   = lane & 15;
    const int base = blockIdx.x * 64;

    // stage h -> hpk (fp16 pairs). b32 writes, stride 38 -> spread banks.
    {
        int sn = tid & 63, sc = tid >> 6;
        int gn = min(base + sn, N - 1);
        const float4* hp = (const float4*)(h + (size_t)gn * D + sc * 16);
        float4 A = hp[0], B = hp[1], C = hp[2], Dv = hp[3];
        unsigned int* wp = hpk + sn * 38 + sc * 8;
        wp[0] = packh2(A.x, A.y);  wp[1] = packh2(A.z, A.w);
        wp[2] = packh2(B.x, B.y);  wp[3] = packh2(B.z, B.w);
        wp[4] = packh2(C.x, C.y);  wp[5] = packh2(C.z, C.w);
        wp[6] = packh2(Dv.x, Dv.y); wp[7] = packh2(Dv.z, Dv.w);
    }
    __syncthreads();

    // A fragments: row = 16w+li; kb=0: k2 in {2g,2g+1}u{8+2g,+1}; kb=1: +16
    FU A0, A1;
    {
        const unsigned int* ap = hpk + (16 * w + li) * 38;
        uint2 x0 = *(const uint2*)(ap + 2 * g);
        uint2 x1 = *(const uint2*)(ap + 8 + 2 * g);
        uint2 x2 = *(const uint2*)(ap + 16 + 2 * g);
        uint2 x3 = *(const uint2*)(ap + 24 + 2 * g);
        A0.u = make_uint4(x0.x, x0.y, x1.x, x1.y);
        A1.u = make_uint4(x2.x, x2.y, x3.x, x3.y);
    }

    // phase 1: 8 col-tiles x (2 MFMA over K=64)
    f32x4v acc[8];
#pragma unroll
    for (int ct = 0; ct < 8; ++ct) {
        FU b0, b1;
        b0.u = ((const uint4*)waf)[(ct * 2 + 0) * 64 + lane];
        b1.u = ((const uint4*)waf)[(ct * 2 + 1) * 64 + lane];
        f32x4v a = {0.f, 0.f, 0.f, 0.f};
        a = __builtin_amdgcn_mfma_f32_16x16x32_f16(A0.h, b0.h, a, 0, 0, 0);
        a = __builtin_amdgcn_mfma_f32_16x16x32_f16(A1.h, b1.h, a, 0, 0, 0);
        acc[ct] = a;
    }

    // bias + relu -> Pf[node][hid]  (C/D: row=4g+r -> node, col=li -> hid)
#pragma unroll
    for (int ct = 0; ct < 8; ++ct) {
        float bav = ba[ct * 16 + li];
#pragma unroll
        for (int r = 0; r < 4; ++r) {
            int node = 16 * w + 4 * g + r;
            Pf[node * 132 + ct * 16 + li] = fmaxf(acc[ct][r] + bav, 0.f);
        }
    }
    __syncthreads();

    // phase 2: A-frag from Pf rows (2 x b128 + cvt_pk per K-block)
    f32x4v acc2[4];
#pragma unroll
    for (int c2 = 0; c2 < 4; ++c2) acc2[c2] = (f32x4v){0.f, 0.f, 0.f, 0.f};

    const float* pp = Pf + (16 * w + li) * 132;
#pragma unroll
    for (int kb = 0; kb < 4; ++kb) {
        float4 plo = *(const float4*)(pp + 32 * kb + 4 * g);
        float4 phi = *(const float4*)(pp + 32 * kb + 16 + 4 * g);
        FU Af;
        Af.u = make_uint4(packh2(plo.x, plo.y), packh2(plo.z, plo.w),
                          packh2(phi.x, phi.y), packh2(phi.z, phi.w));
#pragma unroll
        for (int c2 = 0; c2 < 4; ++c2) {
            FU b;
            b.u = ((const uint4*)wbf)[(c2 * 4 + kb) * 64 + lane];
            acc2[c2] = __builtin_amdgcn_mfma_f32_16x16x32_f16(Af.h, b.h, acc2[c2], 0, 0, 0);
        }
    }

    // epilogue: bias + SiLU + LN + fp16 store
    float sv[4] = {0.f, 0.f, 0.f, 0.f};
    float qv[4] = {0.f, 0.f, 0.f, 0.f};
#pragma unroll
    for (int c2 = 0; c2 < 4; ++c2) {
        float bbv = bb[c2 * 16 + li];
#pragma unroll
        for (int r = 0; r < 4; ++r) {
            float t = acc2[c2][r] + bbv;
            t = t / (1.f + __expf(-t));
            acc2[c2][r] = t;
            sv[r] += t;
            qv[r] = fmaf(t, t, qv[r]);
        }
    }
#pragma unroll
    for (int d2 = 1; d2 < 16; d2 <<= 1) {
#pragma unroll
        for (int r = 0; r < 4; ++r) {
            sv[r] += __shfl_xor(sv[r], d2, 64);
            qv[r] += __shfl_xor(qv[r], d2, 64);
        }
    }
#pragma unroll
    for (int r = 0; r < 4; ++r) {
        int node = base + 16 * w + 4 * g + r;
        if (node < N) {
            float mu  = sv[r] * (1.f / D);
            float var = qv[r] * (1.f / D) - mu * mu;
            float inv = rsqrtf(var + EPSL);
#pragma unroll
            for (int c2 = 0; c2 < 4; ++c2) {
                m[(size_t)node * D + c2 * 16 + li] =
                    __float2half((acc2[c2][r] - mu) * inv);
            }
        }
    }
}

// =======================================================================
// Initial embedding (round-7 proven, unchanged; fp32 h output).
// =======================================================================
__global__ __launch_bounds__(256) void k_init(const float* __restrict__ x,
                                              const float* __restrict__ w0,  // [16][64]
                                              const float* __restrict__ b0,
                                              const float* __restrict__ w1,  // [64][64]
                                              const float* __restrict__ b1,
                                              float* __restrict__ h, int N)
{
    __shared__ __align__(16) float xT[D_IN * 64];
    __shared__ __align__(16) float gT[D * 64];

    const int tid  = threadIdx.x;
    const int ch   = tid & 15;
    const int q    = tid >> 4;
    const int base = blockIdx.x * 64;

    {
        int sn = tid & 63;
        int sc = tid >> 6;
        int gn = min(base + sn, N - 1);
        float4 xv = *(const float4*)(x + (size_t)gn * D_IN + sc * 4);
        float* w = xT + (sc * 4) * 64 + sn;
        w[0*64] = xv.x; w[1*64] = xv.y; w[2*64] = xv.z; w[3*64] = xv.w;
    }
    __syncthreads();

    float acc[4][4];
#pragma unroll
    for (int i = 0; i < 4; ++i)
#pragma unroll
        for (int c = 0; c < 4; ++c) acc[i][c] = 0.f;

#pragma unroll
    for (int k = 0; k < D_IN; ++k) {
        float4 w = *(const float4*)(w0 + k * D + ch * 4);
        float4 xv = *(const float4*)(xT + k * 64 + q * 4);
#define PP(i, xc) \
        acc[i][0]=fmaf(xc,w.x,acc[i][0]); acc[i][1]=fmaf(xc,w.y,acc[i][1]); \
        acc[i][2]=fmaf(xc,w.z,acc[i][2]); acc[i][3]=fmaf(xc,w.w,acc[i][3]);
        PP(0, xv.x) PP(1, xv.y) PP(2, xv.z) PP(3, xv.w)
#undef PP
    }

    {
        float4 b0v = *(const float4*)(b0 + ch * 4);
        float bav[4] = {b0v.x, b0v.y, b0v.z, b0v.w};
        int chunk = q ^ (ch >> 1);      // r = 4ch+c -> r>>3 = ch>>1
#pragma unroll
        for (int c = 0; c < 4; ++c) {
            int r = ch * 4 + c;
            float4 t;
            t.x = fmaxf(acc[0][c] + bav[c], 0.f);
            t.y = fmaxf(acc[1][c] + bav[c], 0.f);
            t.z = fmaxf(acc[2][c] + bav[c], 0.f);
            t.w = fmaxf(acc[3][c] + bav[c], 0.f);
            *(float4*)(gT + r * 64 + chunk * 4) = t;
        }
    }
    __syncthreads();

    float4 o0 = {0,0,0,0}, o1 = {0,0,0,0}, o2 = {0,0,0,0}, o3 = {0,0,0,0};
#pragma unroll 8
    for (int k = 0; k < D; ++k) {
        float4 w = *(const float4*)(w1 + k * D + ch * 4);
        int chunk = q ^ ((k >> 3) & 15);
        float4 g = *(const float4*)(gT + k * 64 + chunk * 4);
        o0.x=fmaf(g.x,w.x,o0.x); o0.y=fmaf(g.x,w.y,o0.y); o0.z=fmaf(g.x,w.z,o0.z); o0.w=fmaf(g.x,w.w,o0.w);
        o1.x=fmaf(g.y,w.x,o1.x); o1.y=fmaf(g.y,w.y,o1.y); o1.z=fmaf(g.y,w.z,o1.z); o1.w=fmaf(g.y,w.w,o1.w);
        o2.x=fmaf(g.z,w.x,o2.x); o2.y=fmaf(g.z,w.y,o2.y); o2.z=fmaf(g.z,w.z,o2.z); o2.w=fmaf(g.z,w.w,o2.w);
        o3.x=fmaf(g.w,w.x,o3.x); o3.y=fmaf(g.w,w.y,o3.y); o3.z=fmaf(g.w,w.z,o3.z); o3.w=fmaf(g.w,w.w,o3.w);
    }

    float4 bbv = *(const float4*)(b1 + ch * 4);
    float s[4], qv[4];
#define FIN(i, ov) { \
        ov.x += bbv.x; ov.y += bbv.y; ov.z += bbv.z; ov.w += bbv.w; \
        ov.x = ov.x / (1.f + __expf(-ov.x)); ov.y = ov.y / (1.f + __expf(-ov.y)); \
        ov.z = ov.z / (1.f + __expf(-ov.z)); ov.w = ov.w / (1.f + __expf(-ov.w)); \
        s[i]  = (ov.x + ov.y) + (ov.z + ov.w); \
        qv[i] = fmaf(ov.x, ov.x, fmaf(ov.y, ov.y, fmaf(ov.z, ov.z, ov.w * ov.w))); }
    FIN(0, o0) FIN(1, o1) FIN(2, o2) FIN(3, o3)
#undef FIN

#pragma unroll
    for (int d2 = 1; d2 < 16; d2 <<= 1) {
#pragma unroll
        for (int i = 0; i < 4; ++i) {
            s[i]  += __shfl_xor(s[i],  d2, 64);
            qv[i] += __shfl_xor(qv[i], d2, 64);
        }
    }

#pragma unroll
    for (int i = 0; i < 4; ++i) {
        float mu  = s[i] * (1.f / D);
        float var = qv[i] * (1.f / D) - mu * mu;
        float inv = rsqrtf(var + EPSL);
        int node = base + q * 4 + i;
        if (node < N) {
            float4 ov = (i == 0) ? o0 : (i == 1) ? o1 : (i == 2) ? o2 : o3;
            float4 outv;
            outv.x = (ov.x - mu) * inv;
            outv.y = (ov.y - mu) * inv;
            outv.z = (ov.z - mu) * inv;
            outv.w = (ov.w - mu) * inv;
            *(float4*)(h + (size_t)node * D + ch * 4) = outv;
        }
    }
}

// ---------------- aggregation: h += segment_mean(m[src], dst) ------------------
// Round-10 proven: m fp16 (8B per lane per edge); quarter-wave/node, unroll 4.
__global__ __launch_bounds__(256) void k_agg(const __half* __restrict__ m,
                                             const int* __restrict__ csr,
                                             const int* __restrict__ off,
                                             float* __restrict__ h, int N)
{
    int g = threadIdx.x >> 4;
    int c = threadIdx.x & 15;
    int node = blockIdx.x * 16 + g;
    if (node >= N) return;

    int b  = off[node];
    int e2 = off[node + 1];
    float4 s0 = {0.f, 0.f, 0.f, 0.f};
    float4 s1 = {0.f, 0.f, 0.f, 0.f};
    int e = b;
#define GATH(sacc, pv) { \
        float2 u0 = __half22float2(*reinterpret_cast<__half2*>(&pv.x)); \
        float2 u1 = __half22float2(*reinterpret_cast<__half2*>(&pv.y)); \
        sacc.x += u0.x; sacc.y += u0.y; sacc.z += u1.x; sacc.w += u1.y; }
    for (; e + 4 <= e2; e += 4) {
        int sn0 = csr[e], sn1 = csr[e + 1], sn2 = csr[e + 2], sn3 = csr[e + 3];
        int2 p0 = ((const int2*)(m + (size_t)sn0 * D))[c];
        int2 p1 = ((const int2*)(m + (size_t)sn1 * D))[c];
        int2 p2 = ((const int2*)(m + (size_t)sn2 * D))[c];
        int2 p3 = ((const int2*)(m + (size_t)sn3 * D))[c];
        GATH(s0, p0) GATH(s1, p1) GATH(s0, p2) GATH(s1, p3)
    }
    for (; e < e2; ++e) {
        int sn = csr[e];
        int2 p = ((const int2*)(m + (size_t)sn * D))[c];
        GATH(s0, p)
    }
#undef GATH
    s0.x += s1.x; s0.y += s1.y; s0.z += s1.z; s0.w += s1.w;

    float dnm = fmaxf((float)(e2 - b), 1.f);
    float inv = 1.f / dnm;

    float4* hp = (float4*)(h + (size_t)node * D);
    float4 hv = hp[c];
    hv.x = fmaf(s0.x, inv, hv.x);
    hv.y = fmaf(s0.y, inv, hv.y);
    hv.z = fmaf(s0.z, inv, hv.z);
    hv.w = fmaf(s0.w, inv, hv.w);
    hp[c] = hv;
}

extern "C" void kernel_launch(void* const* d_in, const int* in_sizes, int n_in,
                              void* d_out, int out_size, void* d_ws, size_t ws_size,
                              hipStream_t stream)
{
    const float* x  = (const float*)d_in[0];
    const int*   ei = (const int*)d_in[1];
    const float* w0 = (const float*)d_in[2];
    const float* b0 = (const float*)d_in[3];
    const float* w1 = (const float*)d_in[4];
    const float* b1 = (const float*)d_in[5];
    const float* wa = (const float*)d_in[6];
    const float* ba = (const float*)d_in[7];
    const float* wb = (const float*)d_in[8];
    const float* bb = (const float*)d_in[9];

    const int N = in_sizes[0] / D_IN;
    const int E = in_sizes[1] / 2;
    const int L = in_sizes[6] / (D * H);

    const int* src = ei;
    const int* dst = ei + E;

    // workspace layout (256B aligned chunks)
    char* ws = (char*)d_ws;
    size_t o = 0;
    auto carve = [&](size_t bytes) -> char* {
        char* p = ws + o;
        o = (o + bytes + 255) & ~(size_t)255;
        return p;
    };
    __half* m          = (__half*)carve((size_t)N * D * sizeof(__half));
    int*   csr         = (int*)  carve((size_t)E * sizeof(int));
    int*   cnt         = (int*)  carve((size_t)N * sizeof(int));
    int*   fill        = (int*)  carve((size_t)N * sizeof(int));
    int*   offp        = (int*)  carve((size_t)(N + 1) * sizeof(int));
    int*   bsum        = (int*)  carve((size_t)1024 * sizeof(int));
    unsigned int* waf  = (unsigned int*)carve((size_t)L * 4096 * sizeof(unsigned int));
    unsigned int* wbf  = (unsigned int*)carve((size_t)L * 4096 * sizeof(unsigned int));

    float* h = (float*)d_out;

    const int nb = (N + 63) / 64;
    const int G1 = (N + 255) / 256;

    k_zero2<<<(N + 255) / 256, 256, 0, stream>>>(cnt, fill, N);
    k_hist<<<(E + 255) / 256, 256, 0, stream>>>(dst, cnt, E);
    k_scan_blk<<<G1, 256, 0, stream>>>(cnt, offp, bsum, N);
    k_scan_top<<<1, 1024, 0, stream>>>(bsum, G1);
    k_scan_add<<<G1, 256, 0, stream>>>(offp, bsum, N);
    k_fill_x<<<2048, 256, 0, stream>>>(src, dst, offp, fill, csr, E);
    k_prep_w<<<(L * 8192 + 255) / 256, 256, 0, stream>>>(wa, wb, waf, wbf, L);

    k_init<<<nb, 256, 0, stream>>>(x, w0, b0, w1, b1, h, N);

    for (int l = 0; l < L; ++l) {
        k_mlp<<<nb, 256, 0, stream>>>(h, waf + (size_t)l * 4096,
                                      ba + (size_t)l * H,
                                      wbf + (size_t)l * 4096,
                                      bb + (size_t)l * D, m, N);
        k_agg<<<(N + 15) / 16, 256, 0, stream>>>(m, csr, offp, h, N);
    }
}

// Round 15
// 248.912 us; speedup vs baseline: 1.3166x; 1.0060x over previous
//
#include <hip/hip_runtime.h>
#include <hip/hip_fp16.h>
#include <math.h>

#define D_IN 16
#define D    64
#define H    128
#define EPSL 1e-5f

typedef _Float16 h2v  __attribute__((ext_vector_type(2)));
typedef _Float16 f16x8 __attribute__((ext_vector_type(8)));
typedef float    f32x4v __attribute__((ext_vector_type(4)));

union FU { uint4 u; f16x8 h; };

__device__ __forceinline__ unsigned int packh2(float x, float y)
{
    __half2 p = __floats2half2_rn(x, y);
    return *reinterpret_cast<unsigned int*>(&p);
}

// =======================================================================
// Preprocessing: hist (4-edge batched, round-13 fill pattern) +
// hierarchical scan + XCD-grouped 4-edge-batched fill.
// =======================================================================

__global__ void k_zero2(int* __restrict__ a, int* __restrict__ b, int n)
{
    int i = blockIdx.x * blockDim.x + threadIdx.x;
    if (i < n) { a[i] = 0; b[i] = 0; }
}

// 4-edge batched histogram: 4 independent no-return atomics in flight/lane.
__global__ void k_hist(const int* __restrict__ dst, int* __restrict__ cnt, int E)
{
    int i0 = (blockIdx.x * blockDim.x + threadIdx.x) * 4;
    if (i0 + 3 < E) {
        int4 d4 = *(const int4*)(dst + i0);
        atomicAdd(&cnt[d4.x], 1);
        atomicAdd(&cnt[d4.y], 1);
        atomicAdd(&cnt[d4.z], 1);
        atomicAdd(&cnt[d4.w], 1);
    } else {
        for (int i = i0; i < E; ++i) atomicAdd(&cnt[dst[i]], 1);
    }
}

__global__ void k_scan_blk(const int* __restrict__ cnt, int* __restrict__ off,
                           int* __restrict__ bsum, int N)
{
    __shared__ int sm[256];
    int t = threadIdx.x;
    int g = blockIdx.x * 256 + t;
    int v = (g < N) ? cnt[g] : 0;
    sm[t] = v;
    __syncthreads();
    for (int d2 = 1; d2 < 256; d2 <<= 1) {
        int u = (t >= d2) ? sm[t - d2] : 0;
        __syncthreads();
        sm[t] += u;
        __syncthreads();
    }
    if (g < N) off[g + 1] = sm[t];
    if (t == 255) bsum[blockIdx.x] = sm[255];
}

__global__ void k_scan_top(int* __restrict__ bsum, int G)
{
    __shared__ int sm[1024];
    int t = threadIdx.x;
    int v = (t < G) ? bsum[t] : 0;
    sm[t] = v;
    __syncthreads();
    for (int d2 = 1; d2 < 1024; d2 <<= 1) {
        int u = (t >= d2) ? sm[t - d2] : 0;
        __syncthreads();
        sm[t] += u;
        __syncthreads();
    }
    if (t < G) bsum[t] = sm[t] - v;   // exclusive
}

__global__ void k_scan_add(int* __restrict__ off, const int* __restrict__ bsum, int N)
{
    int g = blockIdx.x * 256 + threadIdx.x;
    if (g < N) off[g + 1] += bsum[blockIdx.x];
    if (g == 0) off[0] = 0;
}

// XCD-grouped fill, 4-edge batched (round-13 proven). Grid multiple of 8.
__global__ __launch_bounds__(256) void k_fill_x(const int* __restrict__ src,
                                                const int* __restrict__ dst,
                                                const int* __restrict__ off,
                                                int* __restrict__ fill,
                                                int* __restrict__ csr, int E)
{
    int g = blockIdx.x & 7;
    int j = blockIdx.x >> 3;
    int J = gridDim.x >> 3;
    int e0     = (j * 256 + threadIdx.x) * 4;
    int stride = J * 256 * 4;

#define PROC(dv, sv) \
    if (((dv >> 4) & 7) == g) { \
        int o_ = off[dv]; \
        int p_ = atomicAdd(&fill[dv], 1); \
        csr[o_ + p_] = sv; \
    }

    for (int e = e0; e < E; e += stride) {
        if (e + 3 < E) {
            int4 d4 = *(const int4*)(dst + e);
            int4 s4 = *(const int4*)(src + e);
            PROC(d4.x, s4.x)
            PROC(d4.y, s4.y)
            PROC(d4.z, s4.z)
            PROC(d4.w, s4.w)
        } else {
            for (int k = e; k < E; ++k) {
                int dv = dst[k];
                int sv = src[k];
                PROC(dv, sv)
            }
        }
    }
#undef PROC
}

// =======================================================================
// Weight prep v2 (round-14 proven): pack wa/wb into MFMA fragment order.
// =======================================================================
__global__ void k_prep_w(const float* __restrict__ wa, const float* __restrict__ wb,
                         unsigned int* __restrict__ waf, unsigned int* __restrict__ wbf,
                         int L)
{
    int idx = blockIdx.x * blockDim.x + threadIdx.x;
    if (idx >= L * 8192) return;
    int l = idx >> 13;
    int r = idx & 8191;
    bool isA = (r < 4096);
    int r2   = isA ? r : r - 4096;
    int u    = r2 & 3;
    int lane = (r2 >> 2) & 63;
    int t    = r2 >> 8;
    int g  = lane >> 4;
    int li = lane & 15;
    int kk = (u < 2) ? (4 * g + 2 * u) : (16 + 4 * g + 2 * (u - 2));
    if (isA) {
        int kb = t & 1, ct = t >> 1;
        int c  = ct * 16 + li;
        int k0 = kb * 32 + kk;
        const float* bse = wa + (size_t)l * D * H;
        waf[(size_t)l * 4096 + r2] = packh2(bse[k0 * H + c], bse[(k0 + 1) * H + c]);
    } else {
        int kb = t & 3, c2 = t >> 2;
        int j  = c2 * 16 + li;
        int k0 = kb * 32 + kk;
        const float* bse = wb + (size_t)l * H * D;
        wbf[(size_t)l * 4096 + r2] = packh2(bse[k0 * D + j], bse[(k0 + 1) * D + j]);
    }
}

// =======================================================================
// MFMA MLP v5 (round-14 proven, unchanged).
// =======================================================================
__global__ __launch_bounds__(256) void k_mlp(const float* __restrict__ h,
                                             const unsigned int* __restrict__ waf,
                                             const float* __restrict__ ba,
                                             const unsigned int* __restrict__ wbf,
                                             const float* __restrict__ bb,
                                             __half* __restrict__ m, int N)
{
    __shared__ __align__(16) unsigned int hpk[64 * 38];  // 9.5KB fp16-pair h
    __shared__ __align__(16) float        Pf[64 * 132];  // 33.8KB f32 relu-hid

    const int tid  = threadIdx.x;
    const int w    = tid >> 6;          // wave = 16-node stripe
    const int lane = tid & 63;
    const int g    = lane >> 4;
    const int li   = lane & 15;
    const int base = blockIdx.x * 64;

    // stage h -> hpk (fp16 pairs). b32 writes, stride 38 -> spread banks.
    {
        int sn = tid & 63, sc = tid >> 6;
        int gn = min(base + sn, N - 1);
        const float4* hp = (const float4*)(h + (size_t)gn * D + sc * 16);
        float4 A = hp[0], B = hp[1], C = hp[2], Dv = hp[3];
        unsigned int* wp = hpk + sn * 38 + sc * 8;
        wp[0] = packh2(A.x, A.y);  wp[1] = packh2(A.z, A.w);
        wp[2] = packh2(B.x, B.y);  wp[3] = packh2(B.z, B.w);
        wp[4] = packh2(C.x, C.y);  wp[5] = packh2(C.z, C.w);
        wp[6] = packh2(Dv.x, Dv.y); wp[7] = packh2(Dv.z, Dv.w);
    }
    __syncthreads();

    // A fragments: row = 16w+li; kb=0: k2 in {2g,2g+1}u{8+2g,+1}; kb=1: +16
    FU A0, A1;
    {
        const unsigned int* ap = hpk + (16 * w + li) * 38;
        uint2 x0 = *(const uint2*)(ap + 2 * g);
        uint2 x1 = *(const uint2*)(ap + 8 + 2 * g);
        uint2 x2 = *(const uint2*)(ap + 16 + 2 * g);
        uint2 x3 = *(const uint2*)(ap + 24 + 2 * g);
        A0.u = make_uint4(x0.x, x0.y, x1.x, x1.y);
        A1.u = make_uint4(x2.x, x2.y, x3.x, x3.y);
    }

    // phase 1: 8 col-tiles x (2 MFMA over K=64)
    f32x4v acc[8];
#pragma unroll
    for (int ct = 0; ct < 8; ++ct) {
        FU b0, b1;
        b0.u = ((const uint4*)waf)[(ct * 2 + 0) * 64 + lane];
        b1.u = ((const uint4*)waf)[(ct * 2 + 1) * 64 + lane];
        f32x4v a = {0.f, 0.f, 0.f, 0.f};
        a = __builtin_amdgcn_mfma_f32_16x16x32_f16(A0.h, b0.h, a, 0, 0, 0);
        a = __builtin_amdgcn_mfma_f32_16x16x32_f16(A1.h, b1.h, a, 0, 0, 0);
        acc[ct] = a;
    }

    // bias + relu -> Pf[node][hid]  (C/D: row=4g+r -> node, col=li -> hid)
#pragma unroll
    for (int ct = 0; ct < 8; ++ct) {
        float bav = ba[ct * 16 + li];
#pragma unroll
        for (int r = 0; r < 4; ++r) {
            int node = 16 * w + 4 * g + r;
            Pf[node * 132 + ct * 16 + li] = fmaxf(acc[ct][r] + bav, 0.f);
        }
    }
    __syncthreads();

    // phase 2: A-frag from Pf rows (2 x b128 + cvt_pk per K-block)
    f32x4v acc2[4];
#pragma unroll
    for (int c2 = 0; c2 < 4; ++c2) acc2[c2] = (f32x4v){0.f, 0.f, 0.f, 0.f};

    const float* pp = Pf + (16 * w + li) * 132;
#pragma unroll
    for (int kb = 0; kb < 4; ++kb) {
        float4 plo = *(const float4*)(pp + 32 * kb + 4 * g);
        float4 phi = *(const float4*)(pp + 32 * kb + 16 + 4 * g);
        FU Af;
        Af.u = make_uint4(packh2(plo.x, plo.y), packh2(plo.z, plo.w),
                          packh2(phi.x, phi.y), packh2(phi.z, phi.w));
#pragma unroll
        for (int c2 = 0; c2 < 4; ++c2) {
            FU b;
            b.u = ((const uint4*)wbf)[(c2 * 4 + kb) * 64 + lane];
            acc2[c2] = __builtin_amdgcn_mfma_f32_16x16x32_f16(Af.h, b.h, acc2[c2], 0, 0, 0);
        }
    }

    // epilogue: bias + SiLU + LN + fp16 store
    float sv[4] = {0.f, 0.f, 0.f, 0.f};
    float qv[4] = {0.f, 0.f, 0.f, 0.f};
#pragma unroll
    for (int c2 = 0; c2 < 4; ++c2) {
        float bbv = bb[c2 * 16 + li];
#pragma unroll
        for (int r = 0; r < 4; ++r) {
            float t = acc2[c2][r] + bbv;
            t = t / (1.f + __expf(-t));
            acc2[c2][r] = t;
            sv[r] += t;
            qv[r] = fmaf(t, t, qv[r]);
        }
    }
#pragma unroll
    for (int d2 = 1; d2 < 16; d2 <<= 1) {
#pragma unroll
        for (int r = 0; r < 4; ++r) {
            sv[r] += __shfl_xor(sv[r], d2, 64);
            qv[r] += __shfl_xor(qv[r], d2, 64);
        }
    }
#pragma unroll
    for (int r = 0; r < 4; ++r) {
        int node = base + 16 * w + 4 * g + r;
        if (node < N) {
            float mu  = sv[r] * (1.f / D);
            float var = qv[r] * (1.f / D) - mu * mu;
            float inv = rsqrtf(var + EPSL);
#pragma unroll
            for (int c2 = 0; c2 < 4; ++c2) {
                m[(size_t)node * D + c2 * 16 + li] =
                    __float2half((acc2[c2][r] - mu) * inv);
            }
        }
    }
}

// =======================================================================
// Initial embedding (round-7 proven, unchanged; fp32 h output).
// =======================================================================
__global__ __launch_bounds__(256) void k_init(const float* __restrict__ x,
                                              const float* __restrict__ w0,  // [16][64]
                                              const float* __restrict__ b0,
                                              const float* __restrict__ w1,  // [64][64]
                                              const float* __restrict__ b1,
                                              float* __restrict__ h, int N)
{
    __shared__ __align__(16) float xT[D_IN * 64];
    __shared__ __align__(16) float gT[D * 64];

    const int tid  = threadIdx.x;
    const int ch   = tid & 15;
    const int q    = tid >> 4;
    const int base = blockIdx.x * 64;

    {
        int sn = tid & 63;
        int sc = tid >> 6;
        int gn = min(base + sn, N - 1);
        float4 xv = *(const float4*)(x + (size_t)gn * D_IN + sc * 4);
        float* w = xT + (sc * 4) * 64 + sn;
        w[0*64] = xv.x; w[1*64] = xv.y; w[2*64] = xv.z; w[3*64] = xv.w;
    }
    __syncthreads();

    float acc[4][4];
#pragma unroll
    for (int i = 0; i < 4; ++i)
#pragma unroll
        for (int c = 0; c < 4; ++c) acc[i][c] = 0.f;

#pragma unroll
    for (int k = 0; k < D_IN; ++k) {
        float4 w = *(const float4*)(w0 + k * D + ch * 4);
        float4 xv = *(const float4*)(xT + k * 64 + q * 4);
#define PP(i, xc) \
        acc[i][0]=fmaf(xc,w.x,acc[i][0]); acc[i][1]=fmaf(xc,w.y,acc[i][1]); \
        acc[i][2]=fmaf(xc,w.z,acc[i][2]); acc[i][3]=fmaf(xc,w.w,acc[i][3]);
        PP(0, xv.x) PP(1, xv.y) PP(2, xv.z) PP(3, xv.w)
#undef PP
    }

    {
        float4 b0v = *(const float4*)(b0 + ch * 4);
        float bav[4] = {b0v.x, b0v.y, b0v.z, b0v.w};
        int chunk = q ^ (ch >> 1);      // r = 4ch+c -> r>>3 = ch>>1
#pragma unroll
        for (int c = 0; c < 4; ++c) {
            int r = ch * 4 + c;
            float4 t;
            t.x = fmaxf(acc[0][c] + bav[c], 0.f);
            t.y = fmaxf(acc[1][c] + bav[c], 0.f);
            t.z = fmaxf(acc[2][c] + bav[c], 0.f);
            t.w = fmaxf(acc[3][c] + bav[c], 0.f);
            *(float4*)(gT + r * 64 + chunk * 4) = t;
        }
    }
    __syncthreads();

    float4 o0 = {0,0,0,0}, o1 = {0,0,0,0}, o2 = {0,0,0,0}, o3 = {0,0,0,0};
#pragma unroll 8
    for (int k = 0; k < D; ++k) {
        float4 w = *(const float4*)(w1 + k * D + ch * 4);
        int chunk = q ^ ((k >> 3) & 15);
        float4 g = *(const float4*)(gT + k * 64 + chunk * 4);
        o0.x=fmaf(g.x,w.x,o0.x); o0.y=fmaf(g.x,w.y,o0.y); o0.z=fmaf(g.x,w.z,o0.z); o0.w=fmaf(g.x,w.w,o0.w);
        o1.x=fmaf(g.y,w.x,o1.x); o1.y=fmaf(g.y,w.y,o1.y); o1.z=fmaf(g.y,w.z,o1.z); o1.w=fmaf(g.y,w.w,o1.w);
        o2.x=fmaf(g.z,w.x,o2.x); o2.y=fmaf(g.z,w.y,o2.y); o2.z=fmaf(g.z,w.z,o2.z); o2.w=fmaf(g.z,w.w,o2.w);
        o3.x=fmaf(g.w,w.x,o3.x); o3.y=fmaf(g.w,w.y,o3.y); o3.z=fmaf(g.w,w.z,o3.z); o3.w=fmaf(g.w,w.w,o3.w);
    }

    float4 bbv = *(const float4*)(b1 + ch * 4);
    float s[4], qv[4];
#define FIN(i, ov) { \
        ov.x += bbv.x; ov.y += bbv.y; ov.z += bbv.z; ov.w += bbv.w; \
        ov.x = ov.x / (1.f + __expf(-ov.x)); ov.y = ov.y / (1.f + __expf(-ov.y)); \
        ov.z = ov.z / (1.f + __expf(-ov.z)); ov.w = ov.w / (1.f + __expf(-ov.w)); \
        s[i]  = (ov.x + ov.y) + (ov.z + ov.w); \
        qv[i] = fmaf(ov.x, ov.x, fmaf(ov.y, ov.y, fmaf(ov.z, ov.z, ov.w * ov.w))); }
    FIN(0, o0) FIN(1, o1) FIN(2, o2) FIN(3, o3)
#undef FIN

#pragma unroll
    for (int d2 = 1; d2 < 16; d2 <<= 1) {
#pragma unroll
        for (int i = 0; i < 4; ++i) {
            s[i]  += __shfl_xor(s[i],  d2, 64);
            qv[i] += __shfl_xor(qv[i], d2, 64);
        }
    }

#pragma unroll
    for (int i = 0; i < 4; ++i) {
        float mu  = s[i] * (1.f / D);
        float var = qv[i] * (1.f / D) - mu * mu;
        float inv = rsqrtf(var + EPSL);
        int node = base + q * 4 + i;
        if (node < N) {
            float4 ov = (i == 0) ? o0 : (i == 1) ? o1 : (i == 2) ? o2 : o3;
            float4 outv;
            outv.x = (ov.x - mu) * inv;
            outv.y = (ov.y - mu) * inv;
            outv.z = (ov.z - mu) * inv;
            outv.w = (ov.w - mu) * inv;
            *(float4*)(h + (size_t)node * D + ch * 4) = outv;
        }
    }
}

// ---------------- aggregation: h += segment_mean(m[src], dst) ------------------
// Round-15: unroll 8 (was 4) -> 8 independent gather chains in flight per
// lane, ~2 serial iterations at deg~16. csr reads stay scalar (L1-hot,
// 16 lanes share the address). Quarter-wave per node (round-10 proven).
__global__ __launch_bounds__(256) void k_agg(const __half* __restrict__ m,
                                             const int* __restrict__ csr,
                                             const int* __restrict__ off,
                                             float* __restrict__ h, int N)
{
    int g = threadIdx.x >> 4;
    int c = threadIdx.x & 15;
    int node = blockIdx.x * 16 + g;
    if (node >= N) return;

    int b  = off[node];
    int e2 = off[node + 1];
    float4 s0 = {0.f, 0.f, 0.f, 0.f};
    float4 s1 = {0.f, 0.f, 0.f, 0.f};
    int e = b;
#define GATH(sacc, pv) { \
        float2 u0 = __half22float2(*reinterpret_cast<__half2*>(&pv.x)); \
        float2 u1 = __half22float2(*reinterpret_cast<__half2*>(&pv.y)); \
        sacc.x += u0.x; sacc.y += u0.y; sacc.z += u1.x; sacc.w += u1.y; }
    for (; e + 8 <= e2; e += 8) {
        int sn0 = csr[e],     sn1 = csr[e + 1], sn2 = csr[e + 2], sn3 = csr[e + 3];
        int sn4 = csr[e + 4], sn5 = csr[e + 5], sn6 = csr[e + 6], sn7 = csr[e + 7];
        int2 p0 = ((const int2*)(m + (size_t)sn0 * D))[c];
        int2 p1 = ((const int2*)(m + (size_t)sn1 * D))[c];
        int2 p2 = ((const int2*)(m + (size_t)sn2 * D))[c];
        int2 p3 = ((const int2*)(m + (size_t)sn3 * D))[c];
        int2 p4 = ((const int2*)(m + (size_t)sn4 * D))[c];
        int2 p5 = ((const int2*)(m + (size_t)sn5 * D))[c];
        int2 p6 = ((const int2*)(m + (size_t)sn6 * D))[c];
        int2 p7 = ((const int2*)(m + (size_t)sn7 * D))[c];
        GATH(s0, p0) GATH(s1, p1) GATH(s0, p2) GATH(s1, p3)
        GATH(s0, p4) GATH(s1, p5) GATH(s0, p6) GATH(s1, p7)
    }
    for (; e + 2 <= e2; e += 2) {
        int sn0 = csr[e], sn1 = csr[e + 1];
        int2 p0 = ((const int2*)(m + (size_t)sn0 * D))[c];
        int2 p1 = ((const int2*)(m + (size_t)sn1 * D))[c];
        GATH(s0, p0) GATH(s1, p1)
    }
    if (e < e2) {
        int sn = csr[e];
        int2 p = ((const int2*)(m + (size_t)sn * D))[c];
        GATH(s0, p)
    }
#undef GATH
    s0.x += s1.x; s0.y += s1.y; s0.z += s1.z; s0.w += s1.w;

    float dnm = fmaxf((float)(e2 - b), 1.f);
    float inv = 1.f / dnm;

    float4* hp = (float4*)(h + (size_t)node * D);
    float4 hv = hp[c];
    hv.x = fmaf(s0.x, inv, hv.x);
    hv.y = fmaf(s0.y, inv, hv.y);
    hv.z = fmaf(s0.z, inv, hv.z);
    hv.w = fmaf(s0.w, inv, hv.w);
    hp[c] = hv;
}

extern "C" void kernel_launch(void* const* d_in, const int* in_sizes, int n_in,
                              void* d_out, int out_size, void* d_ws, size_t ws_size,
                              hipStream_t stream)
{
    const float* x  = (const float*)d_in[0];
    const int*   ei = (const int*)d_in[1];
    const float* w0 = (const float*)d_in[2];
    const float* b0 = (const float*)d_in[3];
    const float* w1 = (const float*)d_in[4];
    const float* b1 = (const float*)d_in[5];
    const float* wa = (const float*)d_in[6];
    const float* ba = (const float*)d_in[7];
    const float* wb = (const float*)d_in[8];
    const float* bb = (const float*)d_in[9];

    const int N = in_sizes[0] / D_IN;
    const int E = in_sizes[1] / 2;
    const int L = in_sizes[6] / (D * H);

    const int* src = ei;
    const int* dst = ei + E;

    // workspace layout (256B aligned chunks)
    char* ws = (char*)d_ws;
    size_t o = 0;
    auto carve = [&](size_t bytes) -> char* {
        char* p = ws + o;
        o = (o + bytes + 255) & ~(size_t)255;
        return p;
    };
    __half* m          = (__half*)carve((size_t)N * D * sizeof(__half));
    int*   csr         = (int*)  carve((size_t)E * sizeof(int));
    int*   cnt         = (int*)  carve((size_t)N * sizeof(int));
    int*   fill        = (int*)  carve((size_t)N * sizeof(int));
    int*   offp        = (int*)  carve((size_t)(N + 1) * sizeof(int));
    int*   bsum        = (int*)  carve((size_t)1024 * sizeof(int));
    unsigned int* waf  = (unsigned int*)carve((size_t)L * 4096 * sizeof(unsigned int));
    unsigned int* wbf  = (unsigned int*)carve((size_t)L * 4096 * sizeof(unsigned int));

    float* h = (float*)d_out;

    const int nb = (N + 63) / 64;
    const int G1 = (N + 255) / 256;

    k_zero2<<<(N + 255) / 256, 256, 0, stream>>>(cnt, fill, N);
    k_hist<<<(E / 4 + 256) / 256, 256, 0, stream>>>(dst, cnt, E);
    k_scan_blk<<<G1, 256, 0, stream>>>(cnt, offp, bsum, N);
    k_scan_top<<<1, 1024, 0, stream>>>(bsum, G1);
    k_scan_add<<<G1, 256, 0, stream>>>(offp, bsum, N);
    k_fill_x<<<2048, 256, 0, stream>>>(src, dst, offp, fill, csr, E);
    k_prep_w<<<(L * 8192 + 255) / 256, 256, 0, stream>>>(wa, wb, waf, wbf, L);

    k_init<<<nb, 256, 0, stream>>>(x, w0, b0, w1, b1, h, N);

    for (int l = 0; l < L; ++l) {
        k_mlp<<<nb, 256, 0, stream>>>(h, waf + (size_t)l * 4096,
                                      ba + (size_t)l * H,
                                      wbf + (size_t)l * 4096,
                                      bb + (size_t)l * D, m, N);
        k_agg<<<(N + 15) / 16, 256, 0, stream>>>(m, csr, offp, h, N);
    }
}